// Round 8
// baseline (1063.905 us; speedup 1.0000x reference)
//
#include <hip/hip_runtime.h>

typedef unsigned short u16;
typedef unsigned int   u32;

#define HID   128
#define HEADS 4
#define CH    128
#define HC    512

// bf16 pack/unpack for INTERNAL workspace tensors only (inputs/outputs f32)
static __device__ __forceinline__ float bf2f(u16 u) {
  union { u32 u; float f; } x;
  x.u = ((u32)u) << 16;
  return x.f;
}
static __device__ __forceinline__ u16 f2bf(float f) {
  union { float f; u32 u; } x;
  x.f = f;
  u32 r = x.u + 0x7fffu + ((x.u >> 16) & 1u);
  return (u16)(r >> 16);
}

// ---------------- zero int buffer ----------------
__global__ void zero_kernel(int* p, int n) {
  int i = blockIdx.x * 256 + threadIdx.x;
  if (i < n) p[i] = 0;
}

// ---------------- CSR: histogram ----------------
__global__ void hist_kernel(const int* dst_idx, int* deg, int E) {
  int e = blockIdx.x * 256 + threadIdx.x;
  if (e < E) atomicAdd(&deg[dst_idx[e]], 1);
}

// ---------------- CSR: single-block scan ----------------
__global__ void scan_kernel(const int* deg, int* row_ptr, int* cursor, int n) {
  __shared__ int buf[256];
  __shared__ int carry_s;
  int tid = threadIdx.x;
  if (tid == 0) {
    carry_s = 0;
    row_ptr[0] = 0;
  }
  __syncthreads();
  for (int base = 0; base < n; base += 256) {
    int i = base + tid;
    int v = 0;
    if (i < n) v = deg[i];
    buf[tid] = v;
    __syncthreads();
    for (int off = 1; off < 256; off <<= 1) {
      int t = 0;
      if (tid >= off) t = buf[tid - off];
      __syncthreads();
      buf[tid] += t;
      __syncthreads();
    }
    int incl = buf[tid] + carry_s;
    if (i < n) {
      row_ptr[i + 1] = incl;
      cursor[i] = incl - v;
    }
    __syncthreads();
    if (tid == 255) carry_s = incl;
    __syncthreads();
  }
}

// ---------------- CSR: scatter ----------------
__global__ void scatter_kernel(const int* src_idx, const int* dst_idx,
                               int* cursor, int* col, int E) {
  int e = blockIdx.x * 256 + threadIdx.x;
  if (e < E) {
    int pos = atomicAdd(&cursor[dst_idx[e]], 1);
    col[pos] = src_idx[e];
  }
}

// ---- q/k/v projection (512 cols), f32 in, bf16-packed out (ws scratch) ----
// block = 256 threads, 16 nodes per block; thread t -> cols 2t, 2t+1
__global__ void proj512_kernel(const float* hX, const float* W,
                               const float* bias, u16* out, int N) {
  __shared__ float lh[16][128];
  int t = threadIdx.x;
  int n0 = blockIdx.x * 16;
  {
    int nl = t >> 4;
    int seg = t & 15;
    int node = n0 + nl;
    float* dstp = &lh[nl][seg * 8];
    if (node < N) {
      const float* srcp = hX + (size_t)node * HID + seg * 8;
      float4 a = *(const float4*)(srcp);
      float4 b = *(const float4*)(srcp + 4);
      dstp[0] = a.x; dstp[1] = a.y; dstp[2] = a.z; dstp[3] = a.w;
      dstp[4] = b.x; dstp[5] = b.y; dstp[6] = b.z; dstp[7] = b.w;
    } else {
      for (int j = 0; j < 8; ++j) dstp[j] = 0.f;
    }
  }
  __syncthreads();

  int col = t * 2;
  float acc0[16];
  float acc1[16];
  for (int nl = 0; nl < 16; ++nl) {
    acc0[nl] = 0.f;
    acc1[nl] = 0.f;
  }
  for (int k = 0; k < 128; ++k) {
    float2 w = *(const float2*)(W + (size_t)k * HC + col);
    for (int nl = 0; nl < 16; ++nl) {
      float hv = lh[nl][k];
      acc0[nl] = fmaf(hv, w.x, acc0[nl]);
      acc1[nl] = fmaf(hv, w.y, acc1[nl]);
    }
  }
  float b0 = bias[col];
  float b1 = bias[col + 1];
  int nmax = N - n0;
  if (nmax > 16) nmax = 16;
  for (int nl = 0; nl < nmax; ++nl) {
    u32 packed = (u32)f2bf(acc0[nl] + b0) | (((u32)f2bf(acc1[nl] + b1)) << 16);
    *(u32*)(out + (size_t)(n0 + nl) * HC + col) = packed;
  }
}

// ---- skip projection (128 cols), f32 in, f32 out -> d_out directly ----
// block = 256, 16 nodes; sub = t>>6 handles 4 nodes, r = t&63 -> cols 2r,2r+1
__global__ void proj128_kernel(const float* hX, const float* W,
                               const float* bias, float* out, int N) {
  __shared__ float lh[16][128];
  int t = threadIdx.x;
  int n0 = blockIdx.x * 16;
  {
    int nl = t >> 4;
    int seg = t & 15;
    int node = n0 + nl;
    float* dstp = &lh[nl][seg * 8];
    if (node < N) {
      const float* srcp = hX + (size_t)node * HID + seg * 8;
      float4 a = *(const float4*)(srcp);
      float4 b = *(const float4*)(srcp + 4);
      dstp[0] = a.x; dstp[1] = a.y; dstp[2] = a.z; dstp[3] = a.w;
      dstp[4] = b.x; dstp[5] = b.y; dstp[6] = b.z; dstp[7] = b.w;
    } else {
      for (int j = 0; j < 8; ++j) dstp[j] = 0.f;
    }
  }
  __syncthreads();

  int sub = t >> 6;
  int r = t & 63;
  int col = r * 2;
  float acc0[4];
  float acc1[4];
  for (int j = 0; j < 4; ++j) {
    acc0[j] = 0.f;
    acc1[j] = 0.f;
  }
  for (int k = 0; k < 128; ++k) {
    float2 w = *(const float2*)(W + (size_t)k * HID + col);
    for (int j = 0; j < 4; ++j) {
      float hv = lh[sub * 4 + j][k];
      acc0[j] = fmaf(hv, w.x, acc0[j]);
      acc1[j] = fmaf(hv, w.y, acc1[j]);
    }
  }
  float b0 = bias[col];
  float b1 = bias[col + 1];
  for (int j = 0; j < 4; ++j) {
    int node = n0 + sub * 4 + j;
    if (node < N) {
      float2 o;
      o.x = acc0[j] + b0;
      o.y = acc1[j] + b1;
      *(float2*)(out + (size_t)node * HID + col) = o;
    }
  }
}

// ---------------- per-edge scores: one wave per dst node ----------------
// lane: head = lane>>4, r = lane&15; q/k are bf16-packed ws buffers
__global__ void score_kernel(const u16* qb, const u16* kb, const int* row_ptr,
                             const int* col_src, float* scores, int N) {
  int node = blockIdx.x * 4 + (threadIdx.x >> 6);
  if (node >= N) return;
  int lane = threadIdx.x & 63;
  int head = lane >> 4;
  int r = lane & 15;
  int foff = head * CH + r * 8;

  float qf[8];
  {
    uint4 raw = *(const uint4*)(qb + (size_t)node * HC + foff);
    qf[0] = bf2f((u16)(raw.x & 0xffffu));
    qf[1] = bf2f((u16)(raw.x >> 16));
    qf[2] = bf2f((u16)(raw.y & 0xffffu));
    qf[3] = bf2f((u16)(raw.y >> 16));
    qf[4] = bf2f((u16)(raw.z & 0xffffu));
    qf[5] = bf2f((u16)(raw.z >> 16));
    qf[6] = bf2f((u16)(raw.w & 0xffffu));
    qf[7] = bf2f((u16)(raw.w >> 16));
  }

  int e0 = row_ptr[node];
  int e1 = row_ptr[node + 1];
  for (int e = e0; e < e1; ++e) {
    int s = col_src[e];
    uint4 raw = *(const uint4*)(kb + (size_t)s * HC + foff);
    float p = 0.f;
    p = fmaf(bf2f((u16)(raw.x & 0xffffu)), qf[0], p);
    p = fmaf(bf2f((u16)(raw.x >> 16)),     qf[1], p);
    p = fmaf(bf2f((u16)(raw.y & 0xffffu)), qf[2], p);
    p = fmaf(bf2f((u16)(raw.y >> 16)),     qf[3], p);
    p = fmaf(bf2f((u16)(raw.z & 0xffffu)), qf[4], p);
    p = fmaf(bf2f((u16)(raw.z >> 16)),     qf[5], p);
    p = fmaf(bf2f((u16)(raw.w & 0xffffu)), qf[6], p);
    p = fmaf(bf2f((u16)(raw.w >> 16)),     qf[7], p);
    p += __shfl_xor(p, 1);
    p += __shfl_xor(p, 2);
    p += __shfl_xor(p, 4);
    p += __shfl_xor(p, 8);
    if (r == 0) scores[(size_t)e * HEADS + head] = p * 0.08838834764831845f;
  }
}

// ------- softmax + aggregate v; d_out (f32) already holds skip; RMW add -----
__global__ void attn_kernel(const float* scores, const u16* vb,
                            const int* row_ptr, const int* col_src,
                            float* out, int N) {
  int node = blockIdx.x * 4 + (threadIdx.x >> 6);
  if (node >= N) return;
  int lane = threadIdx.x & 63;
  int head = lane >> 4;
  int r = lane & 15;
  int foff = head * CH + r * 8;

  float m = -3.402823466e38f;
  float l = 0.f;
  float acc[8];
  for (int j = 0; j < 8; ++j) acc[j] = 0.f;

  int e0 = row_ptr[node];
  int e1 = row_ptr[node + 1];
  for (int e = e0; e < e1; ++e) {
    float sc = scores[(size_t)e * HEADS + head];
    int s = col_src[e];
    uint4 raw = *(const uint4*)(vb + (size_t)s * HC + foff);
    float vf[8];
    vf[0] = bf2f((u16)(raw.x & 0xffffu));
    vf[1] = bf2f((u16)(raw.x >> 16));
    vf[2] = bf2f((u16)(raw.y & 0xffffu));
    vf[3] = bf2f((u16)(raw.y >> 16));
    vf[4] = bf2f((u16)(raw.z & 0xffffu));
    vf[5] = bf2f((u16)(raw.z >> 16));
    vf[6] = bf2f((u16)(raw.w & 0xffffu));
    vf[7] = bf2f((u16)(raw.w >> 16));
    float mnew = fmaxf(m, sc);
    float scale = expf(m - mnew);
    float pe = expf(sc - mnew);
    l = l * scale + pe;
    for (int j = 0; j < 8; ++j) acc[j] = fmaf(acc[j], scale, pe * vf[j]);
    m = mnew;
  }

  float inv = 0.f;
  if (l > 0.f) inv = 1.0f / l;
  float val[8];
  for (int j = 0; j < 8; ++j) {
    float x = acc[j] * inv;
    x += __shfl_xor(x, 16);
    x += __shfl_xor(x, 32);
    val[j] = x * 0.25f;  // mean over 4 heads
  }

  if (head == 0) {
    float* p = out + (size_t)node * HID + r * 8;
    float4 a = *(const float4*)(p);
    float4 b = *(const float4*)(p + 4);
    a.x += val[0]; a.y += val[1]; a.z += val[2]; a.w += val[3];
    b.x += val[4]; b.y += val[5]; b.z += val[6]; b.w += val[7];
    *(float4*)(p) = a;
    *(float4*)(p + 4) = b;
  }
}

// ---------------- cvec = h_t @ Wup[128:256] + bup (all f32) ----------------
__global__ void cvec_kernel(const float* h_t, const float* Wup,
                            const float* bup, float* cvec) {
  int c = threadIdx.x;  // 128 threads
  float acc = bup[c];
  for (int k = 0; k < 128; ++k)
    acc = fmaf(h_t[k], Wup[(size_t)(128 + k) * 128 + c], acc);
  cvec[c] = acc;
}

// ------- update GEMM + relu + LayerNorm, in-place on d_out (f32) -------
__global__ void ATTLayer_19396072308956_kernel(float* out, const float* Wup,
                                               const float* cvec,
                                               const float* gamma,
                                               const float* beta, int N) {
  __shared__ float lds[4][128];
  int wid = threadIdx.x >> 6;
  int lane = threadIdx.x & 63;
  int node = blockIdx.x * 4 + wid;
  if (node >= N) return;

  float2 hv2 = *(const float2*)(out + (size_t)node * HID + 2 * lane);
  lds[wid][2 * lane] = hv2.x;
  lds[wid][2 * lane + 1] = hv2.y;
  __syncthreads();

  float2 cv = *(const float2*)(cvec + 2 * lane);
  float acc0 = cv.x;
  float acc1 = cv.y;
  for (int k = 0; k < 128; ++k) {
    float2 w = *(const float2*)(Wup + (size_t)k * 128 + 2 * lane);
    float hv = lds[wid][k];
    acc0 = fmaf(hv, w.x, acc0);
    acc1 = fmaf(hv, w.y, acc1);
  }
  float a0 = fmaxf(acc0, 0.f);
  float a1 = fmaxf(acc1, 0.f);

  float s = a0 + a1;
  for (int msk = 1; msk < 64; msk <<= 1) s += __shfl_xor(s, msk);
  float mean = s * (1.0f / 128.0f);
  float d0 = a0 - mean;
  float d1 = a1 - mean;
  float sq = d0 * d0 + d1 * d1;
  for (int msk = 1; msk < 64; msk <<= 1) sq += __shfl_xor(sq, msk);
  float rstd = rsqrtf(sq * (1.0f / 128.0f) + 1e-5f);

  float2 g = *(const float2*)(gamma + 2 * lane);
  float2 b = *(const float2*)(beta + 2 * lane);
  float2 o;
  o.x = d0 * rstd * g.x + b.x;
  o.y = d1 * rstd * g.y + b.y;
  *(float2*)(out + (size_t)node * HID + 2 * lane) = o;
}

extern "C" void kernel_launch(void* const* d_in, const int* in_sizes, int n_in,
                              void* d_out, int out_size, void* d_ws,
                              size_t ws_size, hipStream_t stream) {
  (void)n_in;
  (void)out_size;
  (void)ws_size;

  // All float tensors are float32 per the reference dtypes (round-7 probe:
  // gamma's u16 view is [0x0000, 0x3F80, ...] = f32 ones, NOT bf16 ones).
  const int* edge_index = (const int*)d_in[0];
  const float* hX    = (const float*)d_in[1];
  const float* h_t   = (const float*)d_in[2];
  const float* Wq    = (const float*)d_in[3];
  const float* bq    = (const float*)d_in[4];
  const float* Wk    = (const float*)d_in[5];
  const float* bk    = (const float*)d_in[6];
  const float* Wv    = (const float*)d_in[7];
  const float* bv    = (const float*)d_in[8];
  const float* Wskip = (const float*)d_in[9];
  const float* bskip = (const float*)d_in[10];
  const float* Wup   = (const float*)d_in[11];
  const float* bup   = (const float*)d_in[12];
  const float* gamma = (const float*)d_in[13];
  const float* beta  = (const float*)d_in[14];

  const int E = in_sizes[0] / 2;
  const int N = in_sizes[1] / HID;
  const int* src_idx = edge_index;
  const int* dst_idx = edge_index + E;

  // ---- workspace layout (~112 MB peak) ----
  char* w = (char*)d_ws;
  size_t off = 0;
  float* cvec = (float*)(w + off);
  off += 256 * 4;
  int* deg = (int*)(w + off);
  off += ((size_t)N * 4 + 255) / 256 * 256;
  int* row_ptr = (int*)(w + off);
  off += ((size_t)(N + 1) * 4 + 255) / 256 * 256;
  int* cursor = (int*)(w + off);
  off += ((size_t)N * 4 + 255) / 256 * 256;
  int* col = (int*)(w + off);
  off += ((size_t)E * 4 + 255) / 256 * 256;
  float* scores = (float*)(w + off);
  off += ((size_t)E * HEADS * 4 + 255) / 256 * 256;
  u16* bigA = (u16*)(w + off);  // q during scoring, then v (bf16-packed)
  off += ((size_t)N * HC * 2 + 255) / 256 * 256;
  u16* bigB = (u16*)(w + off);  // k (bf16-packed)
  off += ((size_t)N * HC * 2 + 255) / 256 * 256;

  float* out = (float*)d_out;

  // ---- CSR build ----
  zero_kernel<<<(N + 255) / 256, 256, 0, stream>>>(deg, N);
  hist_kernel<<<(E + 255) / 256, 256, 0, stream>>>(dst_idx, deg, E);
  scan_kernel<<<1, 256, 0, stream>>>(deg, row_ptr, cursor, N);
  scatter_kernel<<<(E + 255) / 256, 256, 0, stream>>>(src_idx, dst_idx, cursor,
                                                      col, E);

  // ---- cvec (h_t part of the update GEMM; constant across nodes) ----
  cvec_kernel<<<1, 128, 0, stream>>>(h_t, Wup, bup, cvec);

  // ---- q -> bigA, k -> bigB ----
  proj512_kernel<<<(N + 15) / 16, 256, 0, stream>>>(hX, Wq, bq, bigA, N);
  proj512_kernel<<<(N + 15) / 16, 256, 0, stream>>>(hX, Wk, bk, bigB, N);

  // ---- per-edge attention scores ----
  score_kernel<<<(N + 3) / 4, 256, 0, stream>>>(bigA, bigB, row_ptr, col,
                                                scores, N);

  // ---- v -> bigA (q dead now), skip -> d_out (f32) ----
  proj512_kernel<<<(N + 15) / 16, 256, 0, stream>>>(hX, Wv, bv, bigA, N);
  proj128_kernel<<<(N + 15) / 16, 256, 0, stream>>>(hX, Wskip, bskip, out, N);

  // ---- softmax + aggregate v, add into d_out ----
  attn_kernel<<<(N + 3) / 4, 256, 0, stream>>>(scores, bigA, row_ptr, col, out,
                                               N);

  // ---- update GEMM + relu + LayerNorm, in-place on d_out ----
  ATTLayer_19396072308956_kernel<<<(N + 3) / 4, 256, 0, stream>>>(
      out, Wup, cvec, gamma, beta, N);
}

// Round 9
// 863.092 us; speedup vs baseline: 1.2327x; 1.2327x over previous
//
#include <hip/hip_runtime.h>

typedef unsigned short u16;
typedef unsigned int   u32;

#define HID   128
#define HEADS 4
#define CH    128
#define HC    512

// bf16 pack/unpack for INTERNAL workspace tensors only (inputs/outputs f32)
static __device__ __forceinline__ float bf2f(u16 u) {
  union { u32 u; float f; } x;
  x.u = ((u32)u) << 16;
  return x.f;
}
static __device__ __forceinline__ u16 f2bf(float f) {
  union { float f; u32 u; } x;
  x.f = f;
  u32 r = x.u + 0x7fffu + ((x.u >> 16) & 1u);
  return (u16)(r >> 16);
}

// ---------------- zero int buffer ----------------
__global__ void zero_kernel(int* p, int n) {
  int i = blockIdx.x * 256 + threadIdx.x;
  if (i < n) p[i] = 0;
}

// ---------------- CSR: histogram ----------------
__global__ void hist_kernel(const int* dst_idx, int* deg, int E) {
  int e = blockIdx.x * 256 + threadIdx.x;
  if (e < E) atomicAdd(&deg[dst_idx[e]], 1);
}

// ---------------- CSR scan phase 1: per-block sums ----------------
__global__ void blocksum_kernel(const int* deg, int* bsums, int n) {
  __shared__ int buf[256];
  int i = blockIdx.x * 256 + threadIdx.x;
  int v = 0;
  if (i < n) v = deg[i];
  buf[threadIdx.x] = v;
  __syncthreads();
  for (int off = 128; off > 0; off >>= 1) {
    if (threadIdx.x < off) buf[threadIdx.x] += buf[threadIdx.x + off];
    __syncthreads();
  }
  if (threadIdx.x == 0) bsums[blockIdx.x] = buf[0];
}

// ---------------- CSR scan phase 2: exclusive scan of block sums ------------
// single block; nb is small (196 for N=50000) so usually one iteration
__global__ void scanb_kernel(const int* bsums, int* boffs, int nb) {
  __shared__ int buf[256];
  __shared__ int carry_s;
  int tid = threadIdx.x;
  if (tid == 0) carry_s = 0;
  __syncthreads();
  for (int base = 0; base < nb; base += 256) {
    int i = base + tid;
    int v = 0;
    if (i < nb) v = bsums[i];
    buf[tid] = v;
    __syncthreads();
    for (int off = 1; off < 256; off <<= 1) {
      int t = 0;
      if (tid >= off) t = buf[tid - off];
      __syncthreads();
      buf[tid] += t;
      __syncthreads();
    }
    int incl = buf[tid] + carry_s;
    if (i < nb) boffs[i] = incl - v;  // exclusive prefix of block sums
    __syncthreads();
    if (tid == 255) carry_s = incl;
    __syncthreads();
  }
}

// ---------------- CSR scan phase 3: in-block scan + block offset ------------
__global__ void scanfinal_kernel(const int* deg, const int* boffs,
                                 int* row_ptr, int* cursor, int n) {
  __shared__ int buf[256];
  int tid = threadIdx.x;
  int i = blockIdx.x * 256 + tid;
  int v = 0;
  if (i < n) v = deg[i];
  buf[tid] = v;
  __syncthreads();
  for (int off = 1; off < 256; off <<= 1) {
    int t = 0;
    if (tid >= off) t = buf[tid - off];
    __syncthreads();
    buf[tid] += t;
    __syncthreads();
  }
  int incl = buf[tid] + boffs[blockIdx.x];
  if (i < n) {
    row_ptr[i + 1] = incl;
    cursor[i] = incl - v;
  }
  if (i == 0) row_ptr[0] = 0;
}

// ---------------- CSR: scatter ----------------
__global__ void scatter_kernel(const int* src_idx, const int* dst_idx,
                               int* cursor, int* col, int E) {
  int e = blockIdx.x * 256 + threadIdx.x;
  if (e < E) {
    int pos = atomicAdd(&cursor[dst_idx[e]], 1);
    col[pos] = src_idx[e];
  }
}

// ---- q/k/v projection (512 cols), f32 in, bf16-packed out (ws scratch) ----
// block = 256 threads, 16 nodes per block; thread t -> cols 2t, 2t+1
__global__ void proj512_kernel(const float* hX, const float* W,
                               const float* bias, u16* out, int N) {
  __shared__ float lh[16][128];
  int t = threadIdx.x;
  int n0 = blockIdx.x * 16;
  {
    int nl = t >> 4;
    int seg = t & 15;
    int node = n0 + nl;
    float* dstp = &lh[nl][seg * 8];
    if (node < N) {
      const float* srcp = hX + (size_t)node * HID + seg * 8;
      float4 a = *(const float4*)(srcp);
      float4 b = *(const float4*)(srcp + 4);
      dstp[0] = a.x; dstp[1] = a.y; dstp[2] = a.z; dstp[3] = a.w;
      dstp[4] = b.x; dstp[5] = b.y; dstp[6] = b.z; dstp[7] = b.w;
    } else {
      for (int j = 0; j < 8; ++j) dstp[j] = 0.f;
    }
  }
  __syncthreads();

  int col = t * 2;
  float acc0[16];
  float acc1[16];
  for (int nl = 0; nl < 16; ++nl) {
    acc0[nl] = 0.f;
    acc1[nl] = 0.f;
  }
  for (int k = 0; k < 128; ++k) {
    float2 w = *(const float2*)(W + (size_t)k * HC + col);
    for (int nl = 0; nl < 16; ++nl) {
      float hv = lh[nl][k];
      acc0[nl] = fmaf(hv, w.x, acc0[nl]);
      acc1[nl] = fmaf(hv, w.y, acc1[nl]);
    }
  }
  float b0 = bias[col];
  float b1 = bias[col + 1];
  int nmax = N - n0;
  if (nmax > 16) nmax = 16;
  for (int nl = 0; nl < nmax; ++nl) {
    u32 packed = (u32)f2bf(acc0[nl] + b0) | (((u32)f2bf(acc1[nl] + b1)) << 16);
    *(u32*)(out + (size_t)(n0 + nl) * HC + col) = packed;
  }
}

// ---- skip projection (128 cols), f32 in, f32 out -> d_out directly ----
__global__ void proj128_kernel(const float* hX, const float* W,
                               const float* bias, float* out, int N) {
  __shared__ float lh[16][128];
  int t = threadIdx.x;
  int n0 = blockIdx.x * 16;
  {
    int nl = t >> 4;
    int seg = t & 15;
    int node = n0 + nl;
    float* dstp = &lh[nl][seg * 8];
    if (node < N) {
      const float* srcp = hX + (size_t)node * HID + seg * 8;
      float4 a = *(const float4*)(srcp);
      float4 b = *(const float4*)(srcp + 4);
      dstp[0] = a.x; dstp[1] = a.y; dstp[2] = a.z; dstp[3] = a.w;
      dstp[4] = b.x; dstp[5] = b.y; dstp[6] = b.z; dstp[7] = b.w;
    } else {
      for (int j = 0; j < 8; ++j) dstp[j] = 0.f;
    }
  }
  __syncthreads();

  int sub = t >> 6;
  int r = t & 63;
  int col = r * 2;
  float acc0[4];
  float acc1[4];
  for (int j = 0; j < 4; ++j) {
    acc0[j] = 0.f;
    acc1[j] = 0.f;
  }
  for (int k = 0; k < 128; ++k) {
    float2 w = *(const float2*)(W + (size_t)k * HID + col);
    for (int j = 0; j < 4; ++j) {
      float hv = lh[sub * 4 + j][k];
      acc0[j] = fmaf(hv, w.x, acc0[j]);
      acc1[j] = fmaf(hv, w.y, acc1[j]);
    }
  }
  float b0 = bias[col];
  float b1 = bias[col + 1];
  for (int j = 0; j < 4; ++j) {
    int node = n0 + sub * 4 + j;
    if (node < N) {
      float2 o;
      o.x = acc0[j] + b0;
      o.y = acc1[j] + b1;
      *(float2*)(out + (size_t)node * HID + col) = o;
    }
  }
}

// ---------------- per-edge scores: one wave per dst node ----------------
__global__ void score_kernel(const u16* qb, const u16* kb, const int* row_ptr,
                             const int* col_src, float* scores, int N) {
  int node = blockIdx.x * 4 + (threadIdx.x >> 6);
  if (node >= N) return;
  int lane = threadIdx.x & 63;
  int head = lane >> 4;
  int r = lane & 15;
  int foff = head * CH + r * 8;

  float qf[8];
  {
    uint4 raw = *(const uint4*)(qb + (size_t)node * HC + foff);
    qf[0] = bf2f((u16)(raw.x & 0xffffu));
    qf[1] = bf2f((u16)(raw.x >> 16));
    qf[2] = bf2f((u16)(raw.y & 0xffffu));
    qf[3] = bf2f((u16)(raw.y >> 16));
    qf[4] = bf2f((u16)(raw.z & 0xffffu));
    qf[5] = bf2f((u16)(raw.z >> 16));
    qf[6] = bf2f((u16)(raw.w & 0xffffu));
    qf[7] = bf2f((u16)(raw.w >> 16));
  }

  int e0 = row_ptr[node];
  int e1 = row_ptr[node + 1];
  for (int e = e0; e < e1; ++e) {
    int s = col_src[e];
    uint4 raw = *(const uint4*)(kb + (size_t)s * HC + foff);
    float p = 0.f;
    p = fmaf(bf2f((u16)(raw.x & 0xffffu)), qf[0], p);
    p = fmaf(bf2f((u16)(raw.x >> 16)),     qf[1], p);
    p = fmaf(bf2f((u16)(raw.y & 0xffffu)), qf[2], p);
    p = fmaf(bf2f((u16)(raw.y >> 16)),     qf[3], p);
    p = fmaf(bf2f((u16)(raw.z & 0xffffu)), qf[4], p);
    p = fmaf(bf2f((u16)(raw.z >> 16)),     qf[5], p);
    p = fmaf(bf2f((u16)(raw.w & 0xffffu)), qf[6], p);
    p = fmaf(bf2f((u16)(raw.w >> 16)),     qf[7], p);
    p += __shfl_xor(p, 1);
    p += __shfl_xor(p, 2);
    p += __shfl_xor(p, 4);
    p += __shfl_xor(p, 8);
    if (r == 0) scores[(size_t)e * HEADS + head] = p * 0.08838834764831845f;
  }
}

// ------- softmax + aggregate v; d_out (f32) already holds skip; RMW add -----
__global__ void attn_kernel(const float* scores, const u16* vb,
                            const int* row_ptr, const int* col_src,
                            float* out, int N) {
  int node = blockIdx.x * 4 + (threadIdx.x >> 6);
  if (node >= N) return;
  int lane = threadIdx.x & 63;
  int head = lane >> 4;
  int r = lane & 15;
  int foff = head * CH + r * 8;

  float m = -3.402823466e38f;
  float l = 0.f;
  float acc[8];
  for (int j = 0; j < 8; ++j) acc[j] = 0.f;

  int e0 = row_ptr[node];
  int e1 = row_ptr[node + 1];
  for (int e = e0; e < e1; ++e) {
    float sc = scores[(size_t)e * HEADS + head];
    int s = col_src[e];
    uint4 raw = *(const uint4*)(vb + (size_t)s * HC + foff);
    float vf[8];
    vf[0] = bf2f((u16)(raw.x & 0xffffu));
    vf[1] = bf2f((u16)(raw.x >> 16));
    vf[2] = bf2f((u16)(raw.y & 0xffffu));
    vf[3] = bf2f((u16)(raw.y >> 16));
    vf[4] = bf2f((u16)(raw.z & 0xffffu));
    vf[5] = bf2f((u16)(raw.z >> 16));
    vf[6] = bf2f((u16)(raw.w & 0xffffu));
    vf[7] = bf2f((u16)(raw.w >> 16));
    float mnew = fmaxf(m, sc);
    float scale = expf(m - mnew);
    float pe = expf(sc - mnew);
    l = l * scale + pe;
    for (int j = 0; j < 8; ++j) acc[j] = fmaf(acc[j], scale, pe * vf[j]);
    m = mnew;
  }

  float inv = 0.f;
  if (l > 0.f) inv = 1.0f / l;
  float val[8];
  for (int j = 0; j < 8; ++j) {
    float x = acc[j] * inv;
    x += __shfl_xor(x, 16);
    x += __shfl_xor(x, 32);
    val[j] = x * 0.25f;  // mean over 4 heads
  }

  if (head == 0) {
    float* p = out + (size_t)node * HID + r * 8;
    float4 a = *(const float4*)(p);
    float4 b = *(const float4*)(p + 4);
    a.x += val[0]; a.y += val[1]; a.z += val[2]; a.w += val[3];
    b.x += val[4]; b.y += val[5]; b.z += val[6]; b.w += val[7];
    *(float4*)(p) = a;
    *(float4*)(p + 4) = b;
  }
}

// ---------------- cvec = h_t @ Wup[128:256] + bup (all f32) ----------------
__global__ void cvec_kernel(const float* h_t, const float* Wup,
                            const float* bup, float* cvec) {
  int c = threadIdx.x;  // 128 threads
  float acc = bup[c];
  for (int k = 0; k < 128; ++k)
    acc = fmaf(h_t[k], Wup[(size_t)(128 + k) * 128 + c], acc);
  cvec[c] = acc;
}

// ------- update GEMM + relu + LayerNorm, in-place on d_out (f32) -------
__global__ void ATTLayer_19396072308956_kernel(float* out, const float* Wup,
                                               const float* cvec,
                                               const float* gamma,
                                               const float* beta, int N) {
  __shared__ float lds[4][128];
  int wid = threadIdx.x >> 6;
  int lane = threadIdx.x & 63;
  int node = blockIdx.x * 4 + wid;
  if (node >= N) return;

  float2 hv2 = *(const float2*)(out + (size_t)node * HID + 2 * lane);
  lds[wid][2 * lane] = hv2.x;
  lds[wid][2 * lane + 1] = hv2.y;
  __syncthreads();

  float2 cv = *(const float2*)(cvec + 2 * lane);
  float acc0 = cv.x;
  float acc1 = cv.y;
  for (int k = 0; k < 128; ++k) {
    float2 w = *(const float2*)(Wup + (size_t)k * 128 + 2 * lane);
    float hv = lds[wid][k];
    acc0 = fmaf(hv, w.x, acc0);
    acc1 = fmaf(hv, w.y, acc1);
  }
  float a0 = fmaxf(acc0, 0.f);
  float a1 = fmaxf(acc1, 0.f);

  float s = a0 + a1;
  for (int msk = 1; msk < 64; msk <<= 1) s += __shfl_xor(s, msk);
  float mean = s * (1.0f / 128.0f);
  float d0 = a0 - mean;
  float d1 = a1 - mean;
  float sq = d0 * d0 + d1 * d1;
  for (int msk = 1; msk < 64; msk <<= 1) sq += __shfl_xor(sq, msk);
  float rstd = rsqrtf(sq * (1.0f / 128.0f) + 1e-5f);

  float2 g = *(const float2*)(gamma + 2 * lane);
  float2 b = *(const float2*)(beta + 2 * lane);
  float2 o;
  o.x = d0 * rstd * g.x + b.x;
  o.y = d1 * rstd * g.y + b.y;
  *(float2*)(out + (size_t)node * HID + 2 * lane) = o;
}

extern "C" void kernel_launch(void* const* d_in, const int* in_sizes, int n_in,
                              void* d_out, int out_size, void* d_ws,
                              size_t ws_size, hipStream_t stream) {
  (void)n_in;
  (void)out_size;
  (void)ws_size;

  const int* edge_index = (const int*)d_in[0];
  const float* hX    = (const float*)d_in[1];
  const float* h_t   = (const float*)d_in[2];
  const float* Wq    = (const float*)d_in[3];
  const float* bq    = (const float*)d_in[4];
  const float* Wk    = (const float*)d_in[5];
  const float* bk    = (const float*)d_in[6];
  const float* Wv    = (const float*)d_in[7];
  const float* bv    = (const float*)d_in[8];
  const float* Wskip = (const float*)d_in[9];
  const float* bskip = (const float*)d_in[10];
  const float* Wup   = (const float*)d_in[11];
  const float* bup   = (const float*)d_in[12];
  const float* gamma = (const float*)d_in[13];
  const float* beta  = (const float*)d_in[14];

  const int E = in_sizes[0] / 2;
  const int N = in_sizes[1] / HID;
  const int* src_idx = edge_index;
  const int* dst_idx = edge_index + E;
  const int NB = (N + 255) / 256;  // scan blocks

  // ---- workspace layout (~112 MB peak) ----
  char* w = (char*)d_ws;
  size_t off = 0;
  float* cvec = (float*)(w + off);
  off += 256 * 4;
  int* deg = (int*)(w + off);
  off += ((size_t)N * 4 + 255) / 256 * 256;
  int* row_ptr = (int*)(w + off);
  off += ((size_t)(N + 1) * 4 + 255) / 256 * 256;
  int* cursor = (int*)(w + off);
  off += ((size_t)N * 4 + 255) / 256 * 256;
  int* bsums = (int*)(w + off);
  off += ((size_t)NB * 4 + 255) / 256 * 256;
  int* boffs = (int*)(w + off);
  off += ((size_t)NB * 4 + 255) / 256 * 256;
  int* col = (int*)(w + off);
  off += ((size_t)E * 4 + 255) / 256 * 256;
  float* scores = (float*)(w + off);
  off += ((size_t)E * HEADS * 4 + 255) / 256 * 256;
  u16* bigA = (u16*)(w + off);  // q during scoring, then v (bf16-packed)
  off += ((size_t)N * HC * 2 + 255) / 256 * 256;
  u16* bigB = (u16*)(w + off);  // k (bf16-packed)
  off += ((size_t)N * HC * 2 + 255) / 256 * 256;

  float* out = (float*)d_out;

  // ---- CSR build (parallel 3-phase scan; was 210us single-block) ----
  zero_kernel<<<NB, 256, 0, stream>>>(deg, N);
  hist_kernel<<<(E + 255) / 256, 256, 0, stream>>>(dst_idx, deg, E);
  blocksum_kernel<<<NB, 256, 0, stream>>>(deg, bsums, N);
  scanb_kernel<<<1, 256, 0, stream>>>(bsums, boffs, NB);
  scanfinal_kernel<<<NB, 256, 0, stream>>>(deg, boffs, row_ptr, cursor, N);
  scatter_kernel<<<(E + 255) / 256, 256, 0, stream>>>(src_idx, dst_idx, cursor,
                                                      col, E);

  // ---- cvec (h_t part of the update GEMM; constant across nodes) ----
  cvec_kernel<<<1, 128, 0, stream>>>(h_t, Wup, bup, cvec);

  // ---- q -> bigA, k -> bigB ----
  proj512_kernel<<<(N + 15) / 16, 256, 0, stream>>>(hX, Wq, bq, bigA, N);
  proj512_kernel<<<(N + 15) / 16, 256, 0, stream>>>(hX, Wk, bk, bigB, N);

  // ---- per-edge attention scores ----
  score_kernel<<<(N + 3) / 4, 256, 0, stream>>>(bigA, bigB, row_ptr, col,
                                                scores, N);

  // ---- v -> bigA (q dead now), skip -> d_out (f32) ----
  proj512_kernel<<<(N + 15) / 16, 256, 0, stream>>>(hX, Wv, bv, bigA, N);
  proj128_kernel<<<(N + 15) / 16, 256, 0, stream>>>(hX, Wskip, bskip, out, N);

  // ---- softmax + aggregate v, add into d_out ----
  attn_kernel<<<(N + 3) / 4, 256, 0, stream>>>(scores, bigA, row_ptr, col, out,
                                               N);

  // ---- update GEMM + relu + LayerNorm, in-place on d_out ----
  ATTLayer_19396072308956_kernel<<<(N + 3) / 4, 256, 0, stream>>>(
      out, Wup, cvec, gamma, beta, N);
}

// Round 10
// 726.943 us; speedup vs baseline: 1.4635x; 1.1873x over previous
//
#include <hip/hip_runtime.h>

typedef unsigned short u16;
typedef unsigned int   u32;

#define HID   128
#define HEADS 4
#define CH    128
#define HC    512
#define UT    32   // nodes per block in the update GEMM

// bf16 pack/unpack for INTERNAL workspace tensors only (inputs/outputs f32)
static __device__ __forceinline__ float bf2f(u16 u) {
  union { u32 u; float f; } x;
  x.u = ((u32)u) << 16;
  return x.f;
}
static __device__ __forceinline__ u16 f2bf(float f) {
  union { float f; u32 u; } x;
  x.f = f;
  u32 r = x.u + 0x7fffu + ((x.u >> 16) & 1u);
  return (u16)(r >> 16);
}

// ---------------- zero int buffer ----------------
__global__ void zero_kernel(int* p, int n) {
  int i = blockIdx.x * 256 + threadIdx.x;
  if (i < n) p[i] = 0;
}

// ---------------- CSR: histogram ----------------
__global__ void hist_kernel(const int* dst_idx, int* deg, int E) {
  int e = blockIdx.x * 256 + threadIdx.x;
  if (e < E) atomicAdd(&deg[dst_idx[e]], 1);
}

// ---------------- CSR scan phase 1: per-block sums ----------------
__global__ void blocksum_kernel(const int* deg, int* bsums, int n) {
  __shared__ int buf[256];
  int i = blockIdx.x * 256 + threadIdx.x;
  int v = 0;
  if (i < n) v = deg[i];
  buf[threadIdx.x] = v;
  __syncthreads();
  for (int off = 128; off > 0; off >>= 1) {
    if (threadIdx.x < off) buf[threadIdx.x] += buf[threadIdx.x + off];
    __syncthreads();
  }
  if (threadIdx.x == 0) bsums[blockIdx.x] = buf[0];
}

// ---------------- CSR scan phase 2: exclusive scan of block sums ------------
__global__ void scanb_kernel(const int* bsums, int* boffs, int nb) {
  __shared__ int buf[256];
  __shared__ int carry_s;
  int tid = threadIdx.x;
  if (tid == 0) carry_s = 0;
  __syncthreads();
  for (int base = 0; base < nb; base += 256) {
    int i = base + tid;
    int v = 0;
    if (i < nb) v = bsums[i];
    buf[tid] = v;
    __syncthreads();
    for (int off = 1; off < 256; off <<= 1) {
      int t = 0;
      if (tid >= off) t = buf[tid - off];
      __syncthreads();
      buf[tid] += t;
      __syncthreads();
    }
    int incl = buf[tid] + carry_s;
    if (i < nb) boffs[i] = incl - v;  // exclusive prefix of block sums
    __syncthreads();
    if (tid == 255) carry_s = incl;
    __syncthreads();
  }
}

// ---------------- CSR scan phase 3: in-block scan + block offset ------------
__global__ void scanfinal_kernel(const int* deg, const int* boffs,
                                 int* row_ptr, int* cursor, int n) {
  __shared__ int buf[256];
  int tid = threadIdx.x;
  int i = blockIdx.x * 256 + tid;
  int v = 0;
  if (i < n) v = deg[i];
  buf[tid] = v;
  __syncthreads();
  for (int off = 1; off < 256; off <<= 1) {
    int t = 0;
    if (tid >= off) t = buf[tid - off];
    __syncthreads();
    buf[tid] += t;
    __syncthreads();
  }
  int incl = buf[tid] + boffs[blockIdx.x];
  if (i < n) {
    row_ptr[i + 1] = incl;
    cursor[i] = incl - v;
  }
  if (i == 0) row_ptr[0] = 0;
}

// ---------------- CSR: scatter ----------------
__global__ void scatter_kernel(const int* src_idx, const int* dst_idx,
                               int* cursor, int* col, int E) {
  int e = blockIdx.x * 256 + threadIdx.x;
  if (e < E) {
    int pos = atomicAdd(&cursor[dst_idx[e]], 1);
    col[pos] = src_idx[e];
  }
}

// ---- q/k/v projection (512 cols), f32 in, bf16-packed out (ws scratch) ----
__global__ void proj512_kernel(const float* hX, const float* W,
                               const float* bias, u16* out, int N) {
  __shared__ float lh[16][128];
  int t = threadIdx.x;
  int n0 = blockIdx.x * 16;
  {
    int nl = t >> 4;
    int seg = t & 15;
    int node = n0 + nl;
    float* dstp = &lh[nl][seg * 8];
    if (node < N) {
      const float* srcp = hX + (size_t)node * HID + seg * 8;
      float4 a = *(const float4*)(srcp);
      float4 b = *(const float4*)(srcp + 4);
      dstp[0] = a.x; dstp[1] = a.y; dstp[2] = a.z; dstp[3] = a.w;
      dstp[4] = b.x; dstp[5] = b.y; dstp[6] = b.z; dstp[7] = b.w;
    } else {
      for (int j = 0; j < 8; ++j) dstp[j] = 0.f;
    }
  }
  __syncthreads();

  int col = t * 2;
  float acc0[16];
  float acc1[16];
  for (int nl = 0; nl < 16; ++nl) {
    acc0[nl] = 0.f;
    acc1[nl] = 0.f;
  }
  for (int k = 0; k < 128; ++k) {
    float2 w = *(const float2*)(W + (size_t)k * HC + col);
    for (int nl = 0; nl < 16; ++nl) {
      float hv = lh[nl][k];
      acc0[nl] = fmaf(hv, w.x, acc0[nl]);
      acc1[nl] = fmaf(hv, w.y, acc1[nl]);
    }
  }
  float b0 = bias[col];
  float b1 = bias[col + 1];
  int nmax = N - n0;
  if (nmax > 16) nmax = 16;
  for (int nl = 0; nl < nmax; ++nl) {
    u32 packed = (u32)f2bf(acc0[nl] + b0) | (((u32)f2bf(acc1[nl] + b1)) << 16);
    *(u32*)(out + (size_t)(n0 + nl) * HC + col) = packed;
  }
}

// ---- skip projection (128 cols), f32 in, f32 out -> d_out directly ----
__global__ void proj128_kernel(const float* hX, const float* W,
                               const float* bias, float* out, int N) {
  __shared__ float lh[16][128];
  int t = threadIdx.x;
  int n0 = blockIdx.x * 16;
  {
    int nl = t >> 4;
    int seg = t & 15;
    int node = n0 + nl;
    float* dstp = &lh[nl][seg * 8];
    if (node < N) {
      const float* srcp = hX + (size_t)node * HID + seg * 8;
      float4 a = *(const float4*)(srcp);
      float4 b = *(const float4*)(srcp + 4);
      dstp[0] = a.x; dstp[1] = a.y; dstp[2] = a.z; dstp[3] = a.w;
      dstp[4] = b.x; dstp[5] = b.y; dstp[6] = b.z; dstp[7] = b.w;
    } else {
      for (int j = 0; j < 8; ++j) dstp[j] = 0.f;
    }
  }
  __syncthreads();

  int sub = t >> 6;
  int r = t & 63;
  int col = r * 2;
  float acc0[4];
  float acc1[4];
  for (int j = 0; j < 4; ++j) {
    acc0[j] = 0.f;
    acc1[j] = 0.f;
  }
  for (int k = 0; k < 128; ++k) {
    float2 w = *(const float2*)(W + (size_t)k * HID + col);
    for (int j = 0; j < 4; ++j) {
      float hv = lh[sub * 4 + j][k];
      acc0[j] = fmaf(hv, w.x, acc0[j]);
      acc1[j] = fmaf(hv, w.y, acc1[j]);
    }
  }
  float b0 = bias[col];
  float b1 = bias[col + 1];
  for (int j = 0; j < 4; ++j) {
    int node = n0 + sub * 4 + j;
    if (node < N) {
      float2 o;
      o.x = acc0[j] + b0;
      o.y = acc1[j] + b1;
      *(float2*)(out + (size_t)node * HID + col) = o;
    }
  }
}

// ---------------- per-edge scores: one wave per dst node ----------------
__global__ void score_kernel(const u16* qb, const u16* kb, const int* row_ptr,
                             const int* col_src, float* scores, int N) {
  int node = blockIdx.x * 4 + (threadIdx.x >> 6);
  if (node >= N) return;
  int lane = threadIdx.x & 63;
  int head = lane >> 4;
  int r = lane & 15;
  int foff = head * CH + r * 8;

  float qf[8];
  {
    uint4 raw = *(const uint4*)(qb + (size_t)node * HC + foff);
    qf[0] = bf2f((u16)(raw.x & 0xffffu));
    qf[1] = bf2f((u16)(raw.x >> 16));
    qf[2] = bf2f((u16)(raw.y & 0xffffu));
    qf[3] = bf2f((u16)(raw.y >> 16));
    qf[4] = bf2f((u16)(raw.z & 0xffffu));
    qf[5] = bf2f((u16)(raw.z >> 16));
    qf[6] = bf2f((u16)(raw.w & 0xffffu));
    qf[7] = bf2f((u16)(raw.w >> 16));
  }

  int e0 = row_ptr[node];
  int e1 = row_ptr[node + 1];
  for (int e = e0; e < e1; ++e) {
    int s = col_src[e];
    uint4 raw = *(const uint4*)(kb + (size_t)s * HC + foff);
    float p = 0.f;
    p = fmaf(bf2f((u16)(raw.x & 0xffffu)), qf[0], p);
    p = fmaf(bf2f((u16)(raw.x >> 16)),     qf[1], p);
    p = fmaf(bf2f((u16)(raw.y & 0xffffu)), qf[2], p);
    p = fmaf(bf2f((u16)(raw.y >> 16)),     qf[3], p);
    p = fmaf(bf2f((u16)(raw.z & 0xffffu)), qf[4], p);
    p = fmaf(bf2f((u16)(raw.z >> 16)),     qf[5], p);
    p = fmaf(bf2f((u16)(raw.w & 0xffffu)), qf[6], p);
    p = fmaf(bf2f((u16)(raw.w >> 16)),     qf[7], p);
    p += __shfl_xor(p, 1);
    p += __shfl_xor(p, 2);
    p += __shfl_xor(p, 4);
    p += __shfl_xor(p, 8);
    if (r == 0) scores[(size_t)e * HEADS + head] = p * 0.08838834764831845f;
  }
}

// ------- softmax + aggregate v; d_out (f32) already holds skip; RMW add -----
__global__ void attn_kernel(const float* scores, const u16* vb,
                            const int* row_ptr, const int* col_src,
                            float* out, int N) {
  int node = blockIdx.x * 4 + (threadIdx.x >> 6);
  if (node >= N) return;
  int lane = threadIdx.x & 63;
  int head = lane >> 4;
  int r = lane & 15;
  int foff = head * CH + r * 8;

  float m = -3.402823466e38f;
  float l = 0.f;
  float acc[8];
  for (int j = 0; j < 8; ++j) acc[j] = 0.f;

  int e0 = row_ptr[node];
  int e1 = row_ptr[node + 1];
  for (int e = e0; e < e1; ++e) {
    float sc = scores[(size_t)e * HEADS + head];
    int s = col_src[e];
    uint4 raw = *(const uint4*)(vb + (size_t)s * HC + foff);
    float vf[8];
    vf[0] = bf2f((u16)(raw.x & 0xffffu));
    vf[1] = bf2f((u16)(raw.x >> 16));
    vf[2] = bf2f((u16)(raw.y & 0xffffu));
    vf[3] = bf2f((u16)(raw.y >> 16));
    vf[4] = bf2f((u16)(raw.z & 0xffffu));
    vf[5] = bf2f((u16)(raw.z >> 16));
    vf[6] = bf2f((u16)(raw.w & 0xffffu));
    vf[7] = bf2f((u16)(raw.w >> 16));
    float mnew = fmaxf(m, sc);
    float scale = expf(m - mnew);
    float pe = expf(sc - mnew);
    l = l * scale + pe;
    for (int j = 0; j < 8; ++j) acc[j] = fmaf(acc[j], scale, pe * vf[j]);
    m = mnew;
  }

  float inv = 0.f;
  if (l > 0.f) inv = 1.0f / l;
  float val[8];
  for (int j = 0; j < 8; ++j) {
    float x = acc[j] * inv;
    x += __shfl_xor(x, 16);
    x += __shfl_xor(x, 32);
    val[j] = x * 0.25f;  // mean over 4 heads
  }

  if (head == 0) {
    float* p = out + (size_t)node * HID + r * 8;
    float4 a = *(const float4*)(p);
    float4 b = *(const float4*)(p + 4);
    a.x += val[0]; a.y += val[1]; a.z += val[2]; a.w += val[3];
    b.x += val[4]; b.y += val[5]; b.z += val[6]; b.w += val[7];
    *(float4*)(p) = a;
    *(float4*)(p + 4) = b;
  }
}

// ---------------- cvec = h_t @ Wup[128:256] + bup (all f32) ----------------
__global__ void cvec_kernel(const float* h_t, const float* Wup,
                            const float* bup, float* cvec) {
  int c = threadIdx.x;  // 128 threads
  float acc = bup[c];
  for (int k = 0; k < 128; ++k)
    acc = fmaf(h_t[k], Wup[(size_t)(128 + k) * 128 + c], acc);
  cvec[c] = acc;
}

// ------- update GEMM + relu + LayerNorm, in-place on d_out (f32) -------
// Tiled rewrite: 32 nodes/block, Wup staged in LDS in two 64-row phases
// (round-9 profile: old 1-node-per-wave version re-read Wup from L2 per node
// -> 3.2GB L2 traffic, 196us at VALUBusy=11%. This cuts global Wup traffic
// 32x and gives each lane 16 independent FMA chains.)
__global__ __launch_bounds__(256) void ATTLayer_19396072308956_kernel(
    float* out, const float* __restrict__ Wup, const float* __restrict__ cvec,
    const float* __restrict__ gamma, const float* __restrict__ beta, int N) {
  __shared__ float Wl[64 * 128];   // 32KB: one 64-row phase of Wup
  __shared__ float Hl[UT * 128];   // 16KB: 32-node h_att tile
  int t = threadIdx.x;
  int n0 = blockIdx.x * UT;

  // stage H tile (in-place source: d_out currently holds h_att)
  for (int i = t * 4; i < UT * 128; i += 1024) {
    int node = n0 + (i >> 7);
    float4 v;
    if (node < N) {
      v = *(const float4*)(out + (size_t)node * HID + (i & 127));
    } else {
      v.x = 0.f; v.y = 0.f; v.z = 0.f; v.w = 0.f;
    }
    *(float4*)(Hl + i) = v;
  }

  int wv = t >> 6;        // wave 0..3: nodes [wv*8, wv*8+8)
  int r = t & 63;         // lane: cols 2r, 2r+1
  int c0 = 2 * r;
  float2 cv = *(const float2*)(cvec + c0);
  float a0[8];
  float a1[8];
  for (int j = 0; j < 8; ++j) {
    a0[j] = cv.x;
    a1[j] = cv.y;
  }

  for (int ph = 0; ph < 2; ++ph) {
    __syncthreads();
    // stage Wup rows [ph*64, ph*64+64): 8192 floats, 32/thread
    for (int i = t * 4; i < 64 * 128; i += 1024) {
      *(float4*)(Wl + i) = *(const float4*)(Wup + (size_t)ph * 64 * 128 + i);
    }
    __syncthreads();
    const float* hbase = Hl + (wv * 8) * 128 + ph * 64;
#pragma unroll 8
    for (int k = 0; k < 64; ++k) {
      float2 w2 = *(const float2*)(Wl + k * 128 + c0);
      for (int j = 0; j < 8; ++j) {
        float h = hbase[j * 128 + k];
        a0[j] = fmaf(h, w2.x, a0[j]);
        a1[j] = fmaf(h, w2.y, a1[j]);
      }
    }
  }

  float2 g = *(const float2*)(gamma + c0);
  float2 b = *(const float2*)(beta + c0);
  for (int j = 0; j < 8; ++j) {
    int node = n0 + wv * 8 + j;
    float r0 = fmaxf(a0[j], 0.f);
    float r1 = fmaxf(a1[j], 0.f);
    float s = r0 + r1;
    for (int msk = 1; msk < 64; msk <<= 1) s += __shfl_xor(s, msk);
    float mean = s * (1.0f / 128.0f);
    float d0 = r0 - mean;
    float d1 = r1 - mean;
    float sq = d0 * d0 + d1 * d1;
    for (int msk = 1; msk < 64; msk <<= 1) sq += __shfl_xor(sq, msk);
    float rstd = rsqrtf(sq * (1.0f / 128.0f) + 1e-5f);
    if (node < N) {
      float2 o;
      o.x = d0 * rstd * g.x + b.x;
      o.y = d1 * rstd * g.y + b.y;
      *(float2*)(out + (size_t)node * HID + c0) = o;
    }
  }
}

extern "C" void kernel_launch(void* const* d_in, const int* in_sizes, int n_in,
                              void* d_out, int out_size, void* d_ws,
                              size_t ws_size, hipStream_t stream) {
  (void)n_in;
  (void)out_size;
  (void)ws_size;

  const int* edge_index = (const int*)d_in[0];
  const float* hX    = (const float*)d_in[1];
  const float* h_t   = (const float*)d_in[2];
  const float* Wq    = (const float*)d_in[3];
  const float* bq    = (const float*)d_in[4];
  const float* Wk    = (const float*)d_in[5];
  const float* bk    = (const float*)d_in[6];
  const float* Wv    = (const float*)d_in[7];
  const float* bv    = (const float*)d_in[8];
  const float* Wskip = (const float*)d_in[9];
  const float* bskip = (const float*)d_in[10];
  const float* Wup   = (const float*)d_in[11];
  const float* bup   = (const float*)d_in[12];
  const float* gamma = (const float*)d_in[13];
  const float* beta  = (const float*)d_in[14];

  const int E = in_sizes[0] / 2;
  const int N = in_sizes[1] / HID;
  const int* src_idx = edge_index;
  const int* dst_idx = edge_index + E;
  const int NB = (N + 255) / 256;  // scan blocks

  // ---- workspace layout (~112 MB peak) ----
  char* w = (char*)d_ws;
  size_t off = 0;
  float* cvec = (float*)(w + off);
  off += 256 * 4;
  int* deg = (int*)(w + off);
  off += ((size_t)N * 4 + 255) / 256 * 256;
  int* row_ptr = (int*)(w + off);
  off += ((size_t)(N + 1) * 4 + 255) / 256 * 256;
  int* cursor = (int*)(w + off);
  off += ((size_t)N * 4 + 255) / 256 * 256;
  int* bsums = (int*)(w + off);
  off += ((size_t)NB * 4 + 255) / 256 * 256;
  int* boffs = (int*)(w + off);
  off += ((size_t)NB * 4 + 255) / 256 * 256;
  int* col = (int*)(w + off);
  off += ((size_t)E * 4 + 255) / 256 * 256;
  float* scores = (float*)(w + off);
  off += ((size_t)E * HEADS * 4 + 255) / 256 * 256;
  u16* bigA = (u16*)(w + off);  // q during scoring, then v (bf16-packed)
  off += ((size_t)N * HC * 2 + 255) / 256 * 256;
  u16* bigB = (u16*)(w + off);  // k (bf16-packed)
  off += ((size_t)N * HC * 2 + 255) / 256 * 256;

  float* out = (float*)d_out;

  // ---- CSR build (parallel 3-phase scan) ----
  zero_kernel<<<NB, 256, 0, stream>>>(deg, N);
  hist_kernel<<<(E + 255) / 256, 256, 0, stream>>>(dst_idx, deg, E);
  blocksum_kernel<<<NB, 256, 0, stream>>>(deg, bsums, N);
  scanb_kernel<<<1, 256, 0, stream>>>(bsums, boffs, NB);
  scanfinal_kernel<<<NB, 256, 0, stream>>>(deg, boffs, row_ptr, cursor, N);
  scatter_kernel<<<(E + 255) / 256, 256, 0, stream>>>(src_idx, dst_idx, cursor,
                                                      col, E);

  // ---- cvec (h_t part of the update GEMM; constant across nodes) ----
  cvec_kernel<<<1, 128, 0, stream>>>(h_t, Wup, bup, cvec);

  // ---- q -> bigA, k -> bigB ----
  proj512_kernel<<<(N + 15) / 16, 256, 0, stream>>>(hX, Wq, bq, bigA, N);
  proj512_kernel<<<(N + 15) / 16, 256, 0, stream>>>(hX, Wk, bk, bigB, N);

  // ---- per-edge attention scores ----
  score_kernel<<<(N + 3) / 4, 256, 0, stream>>>(bigA, bigB, row_ptr, col,
                                                scores, N);

  // ---- v -> bigA (q dead now), skip -> d_out (f32) ----
  proj512_kernel<<<(N + 15) / 16, 256, 0, stream>>>(hX, Wv, bv, bigA, N);
  proj128_kernel<<<(N + 15) / 16, 256, 0, stream>>>(hX, Wskip, bskip, out, N);

  // ---- softmax + aggregate v, add into d_out ----
  attn_kernel<<<(N + 3) / 4, 256, 0, stream>>>(scores, bigA, row_ptr, col, out,
                                               N);

  // ---- update GEMM + relu + LayerNorm, in-place on d_out (tiled) ----
  ATTLayer_19396072308956_kernel<<<(N + UT - 1) / UT, 256, 0, stream>>>(
      out, Wup, cvec, gamma, beta, N);
}

// Round 11
// 461.928 us; speedup vs baseline: 2.3032x; 1.5737x over previous
//
#include <hip/hip_runtime.h>

typedef unsigned short u16;
typedef unsigned int   u32;

#define HID   128
#define HEADS 4
#define CH    128
#define HC    512
#define UT    32   // nodes per block in the update GEMM

typedef __bf16 bf16x8v __attribute__((ext_vector_type(8)));
typedef float  f32x4v  __attribute__((ext_vector_type(4)));
union FragU { uint4 u; bf16x8v b; };

// bf16 pack/unpack for INTERNAL workspace tensors only (inputs/outputs f32)
static __device__ __forceinline__ float bf2f(u16 u) {
  union { u32 u; float f; } x;
  x.u = ((u32)u) << 16;
  return x.f;
}
static __device__ __forceinline__ u16 f2bf(float f) {
  union { float f; u32 u; } x;
  x.f = f;
  u32 r = x.u + 0x7fffu + ((x.u >> 16) & 1u);
  return (u16)(r >> 16);
}

// ---------------- zero int buffer ----------------
__global__ void zero_kernel(int* p, int n) {
  int i = blockIdx.x * 256 + threadIdx.x;
  if (i < n) p[i] = 0;
}

// ---------------- CSR: histogram ----------------
__global__ void hist_kernel(const int* dst_idx, int* deg, int E) {
  int e = blockIdx.x * 256 + threadIdx.x;
  if (e < E) atomicAdd(&deg[dst_idx[e]], 1);
}

// ---------------- CSR scan phase 1: per-block sums ----------------
__global__ void blocksum_kernel(const int* deg, int* bsums, int n) {
  __shared__ int buf[256];
  int i = blockIdx.x * 256 + threadIdx.x;
  int v = 0;
  if (i < n) v = deg[i];
  buf[threadIdx.x] = v;
  __syncthreads();
  for (int off = 128; off > 0; off >>= 1) {
    if (threadIdx.x < off) buf[threadIdx.x] += buf[threadIdx.x + off];
    __syncthreads();
  }
  if (threadIdx.x == 0) bsums[blockIdx.x] = buf[0];
}

// ---------------- CSR scan phase 2: exclusive scan of block sums ------------
__global__ void scanb_kernel(const int* bsums, int* boffs, int nb) {
  __shared__ int buf[256];
  __shared__ int carry_s;
  int tid = threadIdx.x;
  if (tid == 0) carry_s = 0;
  __syncthreads();
  for (int base = 0; base < nb; base += 256) {
    int i = base + tid;
    int v = 0;
    if (i < nb) v = bsums[i];
    buf[tid] = v;
    __syncthreads();
    for (int off = 1; off < 256; off <<= 1) {
      int t = 0;
      if (tid >= off) t = buf[tid - off];
      __syncthreads();
      buf[tid] += t;
      __syncthreads();
    }
    int incl = buf[tid] + carry_s;
    if (i < nb) boffs[i] = incl - v;
    __syncthreads();
    if (tid == 255) carry_s = incl;
    __syncthreads();
  }
}

// ---------------- CSR scan phase 3: in-block scan + block offset ------------
__global__ void scanfinal_kernel(const int* deg, const int* boffs,
                                 int* row_ptr, int* cursor, int n) {
  __shared__ int buf[256];
  int tid = threadIdx.x;
  int i = blockIdx.x * 256 + tid;
  int v = 0;
  if (i < n) v = deg[i];
  buf[tid] = v;
  __syncthreads();
  for (int off = 1; off < 256; off <<= 1) {
    int t = 0;
    if (tid >= off) t = buf[tid - off];
    __syncthreads();
    buf[tid] += t;
    __syncthreads();
  }
  int incl = buf[tid] + boffs[blockIdx.x];
  if (i < n) {
    row_ptr[i + 1] = incl;
    cursor[i] = incl - v;
  }
  if (i == 0) row_ptr[0] = 0;
}

// ---------------- CSR: scatter ----------------
__global__ void scatter_kernel(const int* src_idx, const int* dst_idx,
                               int* cursor, int* col, int E) {
  int e = blockIdx.x * 256 + threadIdx.x;
  if (e < E) {
    int pos = atomicAdd(&cursor[dst_idx[e]], 1);
    col[pos] = src_idx[e];
  }
}

// ---- pack h_X into MFMA A-fragment order (bf16) ----
// frag addr = ((ntile*4 + kc)*64 + lane)*8 + j ; lane = quad*16 + m
// A[m = lane&15][k = kc*32 + quad*8 + j]   (m120-verified A layout)
__global__ void packH_kernel(const float* __restrict__ hX,
                             u16* __restrict__ hpack, int N, int total) {
  int i = blockIdx.x * 256 + threadIdx.x;
  if (i >= total) return;
  int j = i & 7;
  int lane = (i >> 3) & 63;
  int kc = (i >> 9) & 3;
  int ntile = i >> 11;
  int node = ntile * 16 + (lane & 15);
  int k = kc * 32 + (lane >> 4) * 8 + j;
  float v = (node < N) ? hX[(size_t)node * HID + k] : 0.f;
  hpack[i] = f2bf(v);
}

// ---- pack [WA | WB] (f32 row-major k x cols) into B-fragment order (bf16) --
// B[k = kc*32 + quad*8 + j][n = ct*16 + (lane&15)]
__global__ void packW_kernel(const float* __restrict__ WA,
                             const float* __restrict__ WB, int colsA, int ldA,
                             int ldB, u16* __restrict__ Wp, int total) {
  int i = blockIdx.x * 256 + threadIdx.x;
  if (i >= total) return;
  int j = i & 7;
  int lane = (i >> 3) & 63;
  int kc = (i >> 9) & 3;
  int ct = i >> 11;
  int n = ct * 16 + (lane & 15);
  int k = kc * 32 + (lane >> 4) * 8 + j;
  float w = (n < colsA) ? WA[(size_t)k * ldA + n]
                        : WB[(size_t)k * ldB + (n - colsA)];
  Wp[i] = f2bf(w);
}

// ---- MFMA projection: C[64 nodes x 64 cols] per block, 4 waves ----
// wave wv: col-tile ct = blockIdx.y*4+wv, covers 4 node-tiles (16x16 each).
// A,B frags read straight from packed global buffers (lane-contiguous 16B).
// Epilogue: cols<512 -> bf16 outLo (ld HC); cols>=512 -> bf16 outHiB (ld HC)
// or f32 outHiF (ld HID) when hiIsF32 (skip -> d_out).
__global__ __launch_bounds__(256) void mfma_proj_kernel(
    const u16* __restrict__ hpack, const u16* __restrict__ Wp,
    const float* __restrict__ biasLo, const float* __restrict__ biasHi,
    u16* __restrict__ outLo, u16* __restrict__ outHiB,
    float* __restrict__ outHiF, int hiIsF32, int N) {
  int t = threadIdx.x;
  int wv = t >> 6;
  int L = t & 63;
  int ct = blockIdx.y * 4 + wv;
  int nt0 = blockIdx.x * 4;

  f32x4v acc[4];
  for (int mt = 0; mt < 4; ++mt) acc[mt] = (f32x4v){0.f, 0.f, 0.f, 0.f};

  const u16* wb = Wp + (size_t)ct * 2048;       // (ct*4+kc)*512 + L*8
  const u16* hb = hpack + (size_t)nt0 * 2048;   // ((nt0+mt)*4+kc)*512 + L*8

  for (int kc = 0; kc < 4; ++kc) {
    FragU bf;
    bf.u = *(const uint4*)(wb + kc * 512 + L * 8);
    for (int mt = 0; mt < 4; ++mt) {
      FragU af;
      af.u = *(const uint4*)(hb + mt * 2048 + kc * 512 + L * 8);
      acc[mt] =
          __builtin_amdgcn_mfma_f32_16x16x32_bf16(af.b, bf.b, acc[mt], 0, 0, 0);
    }
  }

  // C/D layout (m89-verified): col = lane&15, row = (lane>>4)*4 + reg
  int colq = L & 15;
  int quad = L >> 4;
  int n = ct * 16 + colq;
  float bias = (n < 512) ? biasLo[n] : biasHi[n - 512];
  for (int mt = 0; mt < 4; ++mt) {
    for (int rg = 0; rg < 4; ++rg) {
      int node = (nt0 + mt) * 16 + quad * 4 + rg;
      if (node < N) {
        float val = acc[mt][rg] + bias;
        if (n < 512) {
          outLo[(size_t)node * HC + n] = f2bf(val);
        } else if (hiIsF32) {
          outHiF[(size_t)node * HID + (n - 512)] = val;
        } else {
          outHiB[(size_t)node * HC + (n - 512)] = f2bf(val);
        }
      }
    }
  }
}

// ---------------- per-edge scores: one wave per dst node ----------------
__global__ void score_kernel(const u16* qb, const u16* kb, const int* row_ptr,
                             const int* col_src, float* scores, int N) {
  int node = blockIdx.x * 4 + (threadIdx.x >> 6);
  if (node >= N) return;
  int lane = threadIdx.x & 63;
  int head = lane >> 4;
  int r = lane & 15;
  int foff = head * CH + r * 8;

  float qf[8];
  {
    uint4 raw = *(const uint4*)(qb + (size_t)node * HC + foff);
    qf[0] = bf2f((u16)(raw.x & 0xffffu));
    qf[1] = bf2f((u16)(raw.x >> 16));
    qf[2] = bf2f((u16)(raw.y & 0xffffu));
    qf[3] = bf2f((u16)(raw.y >> 16));
    qf[4] = bf2f((u16)(raw.z & 0xffffu));
    qf[5] = bf2f((u16)(raw.z >> 16));
    qf[6] = bf2f((u16)(raw.w & 0xffffu));
    qf[7] = bf2f((u16)(raw.w >> 16));
  }

  int e0 = row_ptr[node];
  int e1 = row_ptr[node + 1];
  for (int e = e0; e < e1; ++e) {
    int s = col_src[e];
    uint4 raw = *(const uint4*)(kb + (size_t)s * HC + foff);
    float p = 0.f;
    p = fmaf(bf2f((u16)(raw.x & 0xffffu)), qf[0], p);
    p = fmaf(bf2f((u16)(raw.x >> 16)),     qf[1], p);
    p = fmaf(bf2f((u16)(raw.y & 0xffffu)), qf[2], p);
    p = fmaf(bf2f((u16)(raw.y >> 16)),     qf[3], p);
    p = fmaf(bf2f((u16)(raw.z & 0xffffu)), qf[4], p);
    p = fmaf(bf2f((u16)(raw.z >> 16)),     qf[5], p);
    p = fmaf(bf2f((u16)(raw.w & 0xffffu)), qf[6], p);
    p = fmaf(bf2f((u16)(raw.w >> 16)),     qf[7], p);
    p += __shfl_xor(p, 1);
    p += __shfl_xor(p, 2);
    p += __shfl_xor(p, 4);
    p += __shfl_xor(p, 8);
    if (r == 0) scores[(size_t)e * HEADS + head] = p * 0.08838834764831845f;
  }
}

// ------- softmax + aggregate v; d_out (f32) already holds skip; RMW add -----
__global__ void attn_kernel(const float* scores, const u16* vb,
                            const int* row_ptr, const int* col_src,
                            float* out, int N) {
  int node = blockIdx.x * 4 + (threadIdx.x >> 6);
  if (node >= N) return;
  int lane = threadIdx.x & 63;
  int head = lane >> 4;
  int r = lane & 15;
  int foff = head * CH + r * 8;

  float m = -3.402823466e38f;
  float l = 0.f;
  float acc[8];
  for (int j = 0; j < 8; ++j) acc[j] = 0.f;

  int e0 = row_ptr[node];
  int e1 = row_ptr[node + 1];
  for (int e = e0; e < e1; ++e) {
    float sc = scores[(size_t)e * HEADS + head];
    int s = col_src[e];
    uint4 raw = *(const uint4*)(vb + (size_t)s * HC + foff);
    float vf[8];
    vf[0] = bf2f((u16)(raw.x & 0xffffu));
    vf[1] = bf2f((u16)(raw.x >> 16));
    vf[2] = bf2f((u16)(raw.y & 0xffffu));
    vf[3] = bf2f((u16)(raw.y >> 16));
    vf[4] = bf2f((u16)(raw.z & 0xffffu));
    vf[5] = bf2f((u16)(raw.z >> 16));
    vf[6] = bf2f((u16)(raw.w & 0xffffu));
    vf[7] = bf2f((u16)(raw.w >> 16));
    float mnew = fmaxf(m, sc);
    float scale = expf(m - mnew);
    float pe = expf(sc - mnew);
    l = l * scale + pe;
    for (int j = 0; j < 8; ++j) acc[j] = fmaf(acc[j], scale, pe * vf[j]);
    m = mnew;
  }

  float inv = 0.f;
  if (l > 0.f) inv = 1.0f / l;
  float val[8];
  for (int j = 0; j < 8; ++j) {
    float x = acc[j] * inv;
    x += __shfl_xor(x, 16);
    x += __shfl_xor(x, 32);
    val[j] = x * 0.25f;  // mean over 4 heads
  }

  if (head == 0) {
    float* p = out + (size_t)node * HID + r * 8;
    float4 a = *(const float4*)(p);
    float4 b = *(const float4*)(p + 4);
    a.x += val[0]; a.y += val[1]; a.z += val[2]; a.w += val[3];
    b.x += val[4]; b.y += val[5]; b.z += val[6]; b.w += val[7];
    *(float4*)(p) = a;
    *(float4*)(p + 4) = b;
  }
}

// ---------------- cvec = h_t @ Wup[128:256] + bup (all f32) ----------------
__global__ void cvec_kernel(const float* h_t, const float* Wup,
                            const float* bup, float* cvec) {
  int c = threadIdx.x;  // 128 threads
  float acc = bup[c];
  for (int k = 0; k < 128; ++k)
    acc = fmaf(h_t[k], Wup[(size_t)(128 + k) * 128 + c], acc);
  cvec[c] = acc;
}

// ------- update GEMM + relu + LayerNorm, in-place on d_out (f32) -------
// Tiled: 32 nodes/block, Wup staged in LDS in two 64-row phases.
__global__ __launch_bounds__(256) void ATTLayer_19396072308956_kernel(
    float* out, const float* __restrict__ Wup, const float* __restrict__ cvec,
    const float* __restrict__ gamma, const float* __restrict__ beta, int N) {
  __shared__ float Wl[64 * 128];   // 32KB
  __shared__ float Hl[UT * 128];   // 16KB
  int t = threadIdx.x;
  int n0 = blockIdx.x * UT;

  for (int i = t * 4; i < UT * 128; i += 1024) {
    int node = n0 + (i >> 7);
    float4 v;
    if (node < N) {
      v = *(const float4*)(out + (size_t)node * HID + (i & 127));
    } else {
      v.x = 0.f; v.y = 0.f; v.z = 0.f; v.w = 0.f;
    }
    *(float4*)(Hl + i) = v;
  }

  int wv = t >> 6;
  int r = t & 63;
  int c0 = 2 * r;
  float2 cv = *(const float2*)(cvec + c0);
  float a0[8];
  float a1[8];
  for (int j = 0; j < 8; ++j) {
    a0[j] = cv.x;
    a1[j] = cv.y;
  }

  for (int ph = 0; ph < 2; ++ph) {
    __syncthreads();
    for (int i = t * 4; i < 64 * 128; i += 1024) {
      *(float4*)(Wl + i) = *(const float4*)(Wup + (size_t)ph * 64 * 128 + i);
    }
    __syncthreads();
    const float* hbase = Hl + (wv * 8) * 128 + ph * 64;
#pragma unroll 8
    for (int k = 0; k < 64; ++k) {
      float2 w2 = *(const float2*)(Wl + k * 128 + c0);
      for (int j = 0; j < 8; ++j) {
        float h = hbase[j * 128 + k];
        a0[j] = fmaf(h, w2.x, a0[j]);
        a1[j] = fmaf(h, w2.y, a1[j]);
      }
    }
  }

  float2 g = *(const float2*)(gamma + c0);
  float2 b = *(const float2*)(beta + c0);
  for (int j = 0; j < 8; ++j) {
    int node = n0 + wv * 8 + j;
    float r0 = fmaxf(a0[j], 0.f);
    float r1 = fmaxf(a1[j], 0.f);
    float s = r0 + r1;
    for (int msk = 1; msk < 64; msk <<= 1) s += __shfl_xor(s, msk);
    float mean = s * (1.0f / 128.0f);
    float d0 = r0 - mean;
    float d1 = r1 - mean;
    float sq = d0 * d0 + d1 * d1;
    for (int msk = 1; msk < 64; msk <<= 1) sq += __shfl_xor(sq, msk);
    float rstd = rsqrtf(sq * (1.0f / 128.0f) + 1e-5f);
    if (node < N) {
      float2 o;
      o.x = d0 * rstd * g.x + b.x;
      o.y = d1 * rstd * g.y + b.y;
      *(float2*)(out + (size_t)node * HID + c0) = o;
    }
  }
}

extern "C" void kernel_launch(void* const* d_in, const int* in_sizes, int n_in,
                              void* d_out, int out_size, void* d_ws,
                              size_t ws_size, hipStream_t stream) {
  (void)n_in;
  (void)out_size;
  (void)ws_size;

  const int* edge_index = (const int*)d_in[0];
  const float* hX    = (const float*)d_in[1];
  const float* h_t   = (const float*)d_in[2];
  const float* Wq    = (const float*)d_in[3];
  const float* bq    = (const float*)d_in[4];
  const float* Wk    = (const float*)d_in[5];
  const float* bk    = (const float*)d_in[6];
  const float* Wv    = (const float*)d_in[7];
  const float* bv    = (const float*)d_in[8];
  const float* Wskip = (const float*)d_in[9];
  const float* bskip = (const float*)d_in[10];
  const float* Wup   = (const float*)d_in[11];
  const float* bup   = (const float*)d_in[12];
  const float* gamma = (const float*)d_in[13];
  const float* beta  = (const float*)d_in[14];

  const int E = in_sizes[0] / 2;
  const int N = in_sizes[1] / HID;
  const int* src_idx = edge_index;
  const int* dst_idx = edge_index + E;
  const int NB = (N + 255) / 256;
  const int NTILES = (N + 15) / 16;
  const int NTILES4 = ((NTILES + 3) / 4) * 4;

  // ---- workspace layout (~125 MB peak) ----
  char* w = (char*)d_ws;
  size_t off = 0;
  float* cvec = (float*)(w + off);
  off += 256 * 4;
  int* deg = (int*)(w + off);
  off += ((size_t)N * 4 + 255) / 256 * 256;
  int* row_ptr = (int*)(w + off);
  off += ((size_t)(N + 1) * 4 + 255) / 256 * 256;
  int* cursor = (int*)(w + off);
  off += ((size_t)N * 4 + 255) / 256 * 256;
  int* bsums = (int*)(w + off);
  off += ((size_t)NB * 4 + 255) / 256 * 256;
  int* boffs = (int*)(w + off);
  off += ((size_t)NB * 4 + 255) / 256 * 256;
  int* col = (int*)(w + off);
  off += ((size_t)E * 4 + 255) / 256 * 256;
  float* scores = (float*)(w + off);
  off += ((size_t)E * HEADS * 4 + 255) / 256 * 256;
  u16* hpack = (u16*)(w + off);  // h_X in A-fragment order
  off += ((size_t)NTILES4 * 2048 * 2 + 255) / 256 * 256;
  u16* Wp1 = (u16*)(w + off);    // [Wq|Wk] B-fragment order, 1024 cols
  off += ((size_t)128 * 1024 * 2 + 255) / 256 * 256;
  u16* Wp2 = (u16*)(w + off);    // [Wv|Wskip] B-fragment order, 640 cols
  off += ((size_t)128 * 640 * 2 + 255) / 256 * 256;
  u16* bigA = (u16*)(w + off);   // q during scoring, then v (bf16)
  off += ((size_t)N * HC * 2 + 255) / 256 * 256;
  u16* bigB = (u16*)(w + off);   // k (bf16)
  off += ((size_t)N * HC * 2 + 255) / 256 * 256;

  float* out = (float*)d_out;

  // ---- CSR build (parallel 3-phase scan) ----
  zero_kernel<<<NB, 256, 0, stream>>>(deg, N);
  hist_kernel<<<(E + 255) / 256, 256, 0, stream>>>(dst_idx, deg, E);
  blocksum_kernel<<<NB, 256, 0, stream>>>(deg, bsums, N);
  scanb_kernel<<<1, 256, 0, stream>>>(bsums, boffs, NB);
  scanfinal_kernel<<<NB, 256, 0, stream>>>(deg, boffs, row_ptr, cursor, N);
  scatter_kernel<<<(E + 255) / 256, 256, 0, stream>>>(src_idx, dst_idx, cursor,
                                                      col, E);

  // ---- packing for MFMA ----
  int totH = NTILES4 * 2048;
  packH_kernel<<<(totH + 255) / 256, 256, 0, stream>>>(hX, hpack, N, totH);
  packW_kernel<<<(128 * 1024 + 255) / 256, 256, 0, stream>>>(
      Wq, Wk, 512, HC, HC, Wp1, 128 * 1024);
  packW_kernel<<<(128 * 640 + 255) / 256, 256, 0, stream>>>(
      Wv, Wskip, 512, HC, HID, Wp2, 128 * 640);

  // ---- cvec ----
  cvec_kernel<<<1, 128, 0, stream>>>(h_t, Wup, bup, cvec);

  // ---- MFMA projections: q -> bigA, k -> bigB ----
  mfma_proj_kernel<<<dim3(NTILES4 / 4, 16), 256, 0, stream>>>(
      hpack, Wp1, bq, bk, bigA, bigB, (float*)nullptr, 0, N);

  // ---- per-edge attention scores ----
  score_kernel<<<(N + 3) / 4, 256, 0, stream>>>(bigA, bigB, row_ptr, col,
                                                scores, N);

  // ---- MFMA projections: v -> bigA (q dead), skip -> d_out (f32) ----
  mfma_proj_kernel<<<dim3(NTILES4 / 4, 10), 256, 0, stream>>>(
      hpack, Wp2, bv, bskip, bigA, (u16*)nullptr, out, 1, N);

  // ---- softmax + aggregate v, add into d_out ----
  attn_kernel<<<(N + 3) / 4, 256, 0, stream>>>(scores, bigA, row_ptr, col, out,
                                               N);

  // ---- update GEMM + relu + LayerNorm, in-place on d_out (tiled) ----
  ATTLayer_19396072308956_kernel<<<(N + UT - 1) / UT, 256, 0, stream>>>(
      out, Wup, cvec, gamma, beta, N);
}

// Round 12
// 447.867 us; speedup vs baseline: 2.3755x; 1.0314x over previous
//
#include <hip/hip_runtime.h>

typedef unsigned short u16;
typedef unsigned int   u32;

#define HID   128
#define HEADS 4
#define CH    128
#define HC    512
#define UT    32   // nodes per block in the update GEMM

typedef __bf16 bf16x8v __attribute__((ext_vector_type(8)));
typedef float  f32x4v  __attribute__((ext_vector_type(4)));
union FragU { uint4 u; bf16x8v b; };

// bf16 pack/unpack for INTERNAL workspace tensors only (inputs/outputs f32)
static __device__ __forceinline__ float bf2f(u16 u) {
  union { u32 u; float f; } x;
  x.u = ((u32)u) << 16;
  return x.f;
}
static __device__ __forceinline__ u16 f2bf(float f) {
  union { float f; u32 u; } x;
  x.f = f;
  u32 r = x.u + 0x7fffu + ((x.u >> 16) & 1u);
  return (u16)(r >> 16);
}

static __device__ __forceinline__ void unpack8(uint4 raw, float* dst) {
  dst[0] = bf2f((u16)(raw.x & 0xffffu));
  dst[1] = bf2f((u16)(raw.x >> 16));
  dst[2] = bf2f((u16)(raw.y & 0xffffu));
  dst[3] = bf2f((u16)(raw.y >> 16));
  dst[4] = bf2f((u16)(raw.z & 0xffffu));
  dst[5] = bf2f((u16)(raw.z >> 16));
  dst[6] = bf2f((u16)(raw.w & 0xffffu));
  dst[7] = bf2f((u16)(raw.w >> 16));
}

// ---------------- zero int buffer ----------------
__global__ void zero_kernel(int* p, int n) {
  int i = blockIdx.x * 256 + threadIdx.x;
  if (i < n) p[i] = 0;
}

// ---------------- CSR: histogram ----------------
__global__ void hist_kernel(const int* dst_idx, int* deg, int E) {
  int e = blockIdx.x * 256 + threadIdx.x;
  if (e < E) atomicAdd(&deg[dst_idx[e]], 1);
}

// ---------------- CSR scan phase 1: per-block sums ----------------
__global__ void blocksum_kernel(const int* deg, int* bsums, int n) {
  __shared__ int buf[256];
  int i = blockIdx.x * 256 + threadIdx.x;
  int v = 0;
  if (i < n) v = deg[i];
  buf[threadIdx.x] = v;
  __syncthreads();
  for (int off = 128; off > 0; off >>= 1) {
    if (threadIdx.x < off) buf[threadIdx.x] += buf[threadIdx.x + off];
    __syncthreads();
  }
  if (threadIdx.x == 0) bsums[blockIdx.x] = buf[0];
}

// ---------------- CSR scan phase 2: exclusive scan of block sums ------------
__global__ void scanb_kernel(const int* bsums, int* boffs, int nb) {
  __shared__ int buf[256];
  __shared__ int carry_s;
  int tid = threadIdx.x;
  if (tid == 0) carry_s = 0;
  __syncthreads();
  for (int base = 0; base < nb; base += 256) {
    int i = base + tid;
    int v = 0;
    if (i < nb) v = bsums[i];
    buf[tid] = v;
    __syncthreads();
    for (int off = 1; off < 256; off <<= 1) {
      int t = 0;
      if (tid >= off) t = buf[tid - off];
      __syncthreads();
      buf[tid] += t;
      __syncthreads();
    }
    int incl = buf[tid] + carry_s;
    if (i < nb) boffs[i] = incl - v;
    __syncthreads();
    if (tid == 255) carry_s = incl;
    __syncthreads();
  }
}

// ---------------- CSR scan phase 3: in-block scan + block offset ------------
__global__ void scanfinal_kernel(const int* deg, const int* boffs,
                                 int* row_ptr, int* cursor, int n) {
  __shared__ int buf[256];
  int tid = threadIdx.x;
  int i = blockIdx.x * 256 + tid;
  int v = 0;
  if (i < n) v = deg[i];
  buf[tid] = v;
  __syncthreads();
  for (int off = 1; off < 256; off <<= 1) {
    int t = 0;
    if (tid >= off) t = buf[tid - off];
    __syncthreads();
    buf[tid] += t;
    __syncthreads();
  }
  int incl = buf[tid] + boffs[blockIdx.x];
  if (i < n) {
    row_ptr[i + 1] = incl;
    cursor[i] = incl - v;
  }
  if (i == 0) row_ptr[0] = 0;
}

// ---------------- CSR: scatter ----------------
__global__ void scatter_kernel(const int* src_idx, const int* dst_idx,
                               int* cursor, int* col, int E) {
  int e = blockIdx.x * 256 + threadIdx.x;
  if (e < E) {
    int pos = atomicAdd(&cursor[dst_idx[e]], 1);
    col[pos] = src_idx[e];
  }
}

// ---- pack h_X into MFMA A-fragment order (bf16) ----
__global__ void packH_kernel(const float* __restrict__ hX,
                             u16* __restrict__ hpack, int N, int total) {
  int i = blockIdx.x * 256 + threadIdx.x;
  if (i >= total) return;
  int j = i & 7;
  int lane = (i >> 3) & 63;
  int kc = (i >> 9) & 3;
  int ntile = i >> 11;
  int node = ntile * 16 + (lane & 15);
  int k = kc * 32 + (lane >> 4) * 8 + j;
  float v = (node < N) ? hX[(size_t)node * HID + k] : 0.f;
  hpack[i] = f2bf(v);
}

// ---- pack [WA | WB] (f32 row-major k x cols) into B-fragment order (bf16) --
__global__ void packW_kernel(const float* __restrict__ WA,
                             const float* __restrict__ WB, int colsA, int ldA,
                             int ldB, u16* __restrict__ Wp, int total) {
  int i = blockIdx.x * 256 + threadIdx.x;
  if (i >= total) return;
  int j = i & 7;
  int lane = (i >> 3) & 63;
  int kc = (i >> 9) & 3;
  int ct = i >> 11;
  int n = ct * 16 + (lane & 15);
  int k = kc * 32 + (lane >> 4) * 8 + j;
  float w = (n < colsA) ? WA[(size_t)k * ldA + n]
                        : WB[(size_t)k * ldB + (n - colsA)];
  Wp[i] = f2bf(w);
}

// ---- MFMA projection: C[64 nodes x 64 cols] per block, 4 waves ----
__global__ __launch_bounds__(256) void mfma_proj_kernel(
    const u16* __restrict__ hpack, const u16* __restrict__ Wp,
    const float* __restrict__ biasLo, const float* __restrict__ biasHi,
    u16* __restrict__ outLo, u16* __restrict__ outHiB,
    float* __restrict__ outHiF, int hiIsF32, int N) {
  int t = threadIdx.x;
  int wv = t >> 6;
  int L = t & 63;
  int ct = blockIdx.y * 4 + wv;
  int nt0 = blockIdx.x * 4;

  f32x4v acc[4];
  for (int mt = 0; mt < 4; ++mt) acc[mt] = (f32x4v){0.f, 0.f, 0.f, 0.f};

  const u16* wb = Wp + (size_t)ct * 2048;
  const u16* hb = hpack + (size_t)nt0 * 2048;

  for (int kc = 0; kc < 4; ++kc) {
    FragU bf;
    bf.u = *(const uint4*)(wb + kc * 512 + L * 8);
    for (int mt = 0; mt < 4; ++mt) {
      FragU af;
      af.u = *(const uint4*)(hb + mt * 2048 + kc * 512 + L * 8);
      acc[mt] =
          __builtin_amdgcn_mfma_f32_16x16x32_bf16(af.b, bf.b, acc[mt], 0, 0, 0);
    }
  }

  int colq = L & 15;
  int quad = L >> 4;
  int n = ct * 16 + colq;
  float bias = (n < 512) ? biasLo[n] : biasHi[n - 512];
  for (int mt = 0; mt < 4; ++mt) {
    for (int rg = 0; rg < 4; ++rg) {
      int node = (nt0 + mt) * 16 + quad * 4 + rg;
      if (node < N) {
        float val = acc[mt][rg] + bias;
        if (n < 512) {
          outLo[(size_t)node * HC + n] = f2bf(val);
        } else if (hiIsF32) {
          outHiF[(size_t)node * HID + (n - 512)] = val;
        } else {
          outHiB[(size_t)node * HC + (n - 512)] = f2bf(val);
        }
      }
    }
  }
}

// ---- FUSED per-node attention: score + online softmax + v-aggregate --------
// One wave per dst node; 2-edge unroll -> 4x 16B gathers in flight.
// d_out (f32) already holds skip; RMW add of head-mean.
__global__ void fused_attn_kernel(const u16* __restrict__ qb,
                                  const u16* __restrict__ kb,
                                  const u16* __restrict__ vb,
                                  const int* __restrict__ row_ptr,
                                  const int* __restrict__ col_src,
                                  float* out, int N) {
  int node = blockIdx.x * 4 + (threadIdx.x >> 6);
  if (node >= N) return;
  int lane = threadIdx.x & 63;
  int head = lane >> 4;
  int r = lane & 15;
  int foff = head * CH + r * 8;
  const float sscale = 0.08838834764831845f;  // 1/sqrt(128)

  float qf[8];
  unpack8(*(const uint4*)(qb + (size_t)node * HC + foff), qf);

  float m = -3.402823466e38f;
  float l = 0.f;
  float acc[8];
  for (int j = 0; j < 8; ++j) acc[j] = 0.f;

  int e0 = row_ptr[node];
  int e1 = row_ptr[node + 1];
  int e = e0;
  for (; e + 2 <= e1; e += 2) {
    int s0 = col_src[e];
    int s1 = col_src[e + 1];
    uint4 k0 = *(const uint4*)(kb + (size_t)s0 * HC + foff);
    uint4 k1 = *(const uint4*)(kb + (size_t)s1 * HC + foff);
    uint4 v0 = *(const uint4*)(vb + (size_t)s0 * HC + foff);
    uint4 v1 = *(const uint4*)(vb + (size_t)s1 * HC + foff);
    float k0f[8], k1f[8];
    unpack8(k0, k0f);
    unpack8(k1, k1f);
    float p0 = 0.f, p1 = 0.f;
    for (int j = 0; j < 8; ++j) {
      p0 = fmaf(k0f[j], qf[j], p0);
      p1 = fmaf(k1f[j], qf[j], p1);
    }
    p0 += __shfl_xor(p0, 1);
    p1 += __shfl_xor(p1, 1);
    p0 += __shfl_xor(p0, 2);
    p1 += __shfl_xor(p1, 2);
    p0 += __shfl_xor(p0, 4);
    p1 += __shfl_xor(p1, 4);
    p0 += __shfl_xor(p0, 8);
    p1 += __shfl_xor(p1, 8);
    float sc0 = p0 * sscale;
    float sc1 = p1 * sscale;
    float mnew = fmaxf(m, fmaxf(sc0, sc1));
    float so = __expf(m - mnew);
    float pe0 = __expf(sc0 - mnew);
    float pe1 = __expf(sc1 - mnew);
    l = l * so + pe0 + pe1;
    float v0f[8], v1f[8];
    unpack8(v0, v0f);
    unpack8(v1, v1f);
    for (int j = 0; j < 8; ++j)
      acc[j] = fmaf(acc[j], so, fmaf(pe0, v0f[j], pe1 * v1f[j]));
    m = mnew;
  }
  if (e < e1) {  // tail edge
    int s0 = col_src[e];
    uint4 k0 = *(const uint4*)(kb + (size_t)s0 * HC + foff);
    uint4 v0 = *(const uint4*)(vb + (size_t)s0 * HC + foff);
    float k0f[8];
    unpack8(k0, k0f);
    float p0 = 0.f;
    for (int j = 0; j < 8; ++j) p0 = fmaf(k0f[j], qf[j], p0);
    p0 += __shfl_xor(p0, 1);
    p0 += __shfl_xor(p0, 2);
    p0 += __shfl_xor(p0, 4);
    p0 += __shfl_xor(p0, 8);
    float sc0 = p0 * sscale;
    float mnew = fmaxf(m, sc0);
    float so = __expf(m - mnew);
    float pe0 = __expf(sc0 - mnew);
    l = l * so + pe0;
    float v0f[8];
    unpack8(v0, v0f);
    for (int j = 0; j < 8; ++j) acc[j] = fmaf(acc[j], so, pe0 * v0f[j]);
    m = mnew;
  }

  float inv = 0.f;
  if (l > 0.f) inv = 1.0f / l;
  float val[8];
  for (int j = 0; j < 8; ++j) {
    float x = acc[j] * inv;
    x += __shfl_xor(x, 16);
    x += __shfl_xor(x, 32);
    val[j] = x * 0.25f;  // mean over 4 heads
  }

  if (head == 0) {
    float* p = out + (size_t)node * HID + r * 8;
    float4 a = *(const float4*)(p);
    float4 b = *(const float4*)(p + 4);
    a.x += val[0]; a.y += val[1]; a.z += val[2]; a.w += val[3];
    b.x += val[4]; b.y += val[5]; b.z += val[6]; b.w += val[7];
    *(float4*)(p) = a;
    *(float4*)(p + 4) = b;
  }
}

// ---------------- split-path fallback: per-edge scores ----------------
__global__ void score_kernel(const u16* qb, const u16* kb, const int* row_ptr,
                             const int* col_src, float* scores, int N) {
  int node = blockIdx.x * 4 + (threadIdx.x >> 6);
  if (node >= N) return;
  int lane = threadIdx.x & 63;
  int head = lane >> 4;
  int r = lane & 15;
  int foff = head * CH + r * 8;

  float qf[8];
  unpack8(*(const uint4*)(qb + (size_t)node * HC + foff), qf);

  int e0 = row_ptr[node];
  int e1 = row_ptr[node + 1];
  for (int e = e0; e < e1; ++e) {
    int s = col_src[e];
    uint4 raw = *(const uint4*)(kb + (size_t)s * HC + foff);
    float kf[8];
    unpack8(raw, kf);
    float p = 0.f;
    for (int j = 0; j < 8; ++j) p = fmaf(kf[j], qf[j], p);
    p += __shfl_xor(p, 1);
    p += __shfl_xor(p, 2);
    p += __shfl_xor(p, 4);
    p += __shfl_xor(p, 8);
    if (r == 0) scores[(size_t)e * HEADS + head] = p * 0.08838834764831845f;
  }
}

// ---------------- split-path fallback: softmax + aggregate ----------------
__global__ void attn_kernel(const float* scores, const u16* vb,
                            const int* row_ptr, const int* col_src,
                            float* out, int N) {
  int node = blockIdx.x * 4 + (threadIdx.x >> 6);
  if (node >= N) return;
  int lane = threadIdx.x & 63;
  int head = lane >> 4;
  int r = lane & 15;
  int foff = head * CH + r * 8;

  float m = -3.402823466e38f;
  float l = 0.f;
  float acc[8];
  for (int j = 0; j < 8; ++j) acc[j] = 0.f;

  int e0 = row_ptr[node];
  int e1 = row_ptr[node + 1];
  for (int e = e0; e < e1; ++e) {
    float sc = scores[(size_t)e * HEADS + head];
    int s = col_src[e];
    uint4 raw = *(const uint4*)(vb + (size_t)s * HC + foff);
    float vf[8];
    unpack8(raw, vf);
    float mnew = fmaxf(m, sc);
    float scale = __expf(m - mnew);
    float pe = __expf(sc - mnew);
    l = l * scale + pe;
    for (int j = 0; j < 8; ++j) acc[j] = fmaf(acc[j], scale, pe * vf[j]);
    m = mnew;
  }

  float inv = 0.f;
  if (l > 0.f) inv = 1.0f / l;
  float val[8];
  for (int j = 0; j < 8; ++j) {
    float x = acc[j] * inv;
    x += __shfl_xor(x, 16);
    x += __shfl_xor(x, 32);
    val[j] = x * 0.25f;
  }

  if (head == 0) {
    float* p = out + (size_t)node * HID + r * 8;
    float4 a = *(const float4*)(p);
    float4 b = *(const float4*)(p + 4);
    a.x += val[0]; a.y += val[1]; a.z += val[2]; a.w += val[3];
    b.x += val[4]; b.y += val[5]; b.z += val[6]; b.w += val[7];
    *(float4*)(p) = a;
    *(float4*)(p + 4) = b;
  }
}

// ---------------- cvec = h_t @ Wup[128:256] + bup (all f32) ----------------
__global__ void cvec_kernel(const float* h_t, const float* Wup,
                            const float* bup, float* cvec) {
  int c = threadIdx.x;
  float acc = bup[c];
  for (int k = 0; k < 128; ++k)
    acc = fmaf(h_t[k], Wup[(size_t)(128 + k) * 128 + c], acc);
  cvec[c] = acc;
}

// ------- update GEMM + relu + LayerNorm, in-place on d_out (f32) -------
__global__ __launch_bounds__(256) void ATTLayer_19396072308956_kernel(
    float* out, const float* __restrict__ Wup, const float* __restrict__ cvec,
    const float* __restrict__ gamma, const float* __restrict__ beta, int N) {
  __shared__ float Wl[64 * 128];
  __shared__ float Hl[UT * 128];
  int t = threadIdx.x;
  int n0 = blockIdx.x * UT;

  for (int i = t * 4; i < UT * 128; i += 1024) {
    int node = n0 + (i >> 7);
    float4 v;
    if (node < N) {
      v = *(const float4*)(out + (size_t)node * HID + (i & 127));
    } else {
      v.x = 0.f; v.y = 0.f; v.z = 0.f; v.w = 0.f;
    }
    *(float4*)(Hl + i) = v;
  }

  int wv = t >> 6;
  int r = t & 63;
  int c0 = 2 * r;
  float2 cv = *(const float2*)(cvec + c0);
  float a0[8];
  float a1[8];
  for (int j = 0; j < 8; ++j) {
    a0[j] = cv.x;
    a1[j] = cv.y;
  }

  for (int ph = 0; ph < 2; ++ph) {
    __syncthreads();
    for (int i = t * 4; i < 64 * 128; i += 1024) {
      *(float4*)(Wl + i) = *(const float4*)(Wup + (size_t)ph * 64 * 128 + i);
    }
    __syncthreads();
    const float* hbase = Hl + (wv * 8) * 128 + ph * 64;
#pragma unroll 8
    for (int k = 0; k < 64; ++k) {
      float2 w2 = *(const float2*)(Wl + k * 128 + c0);
      for (int j = 0; j < 8; ++j) {
        float h = hbase[j * 128 + k];
        a0[j] = fmaf(h, w2.x, a0[j]);
        a1[j] = fmaf(h, w2.y, a1[j]);
      }
    }
  }

  float2 g = *(const float2*)(gamma + c0);
  float2 b = *(const float2*)(beta + c0);
  for (int j = 0; j < 8; ++j) {
    int node = n0 + wv * 8 + j;
    float r0 = fmaxf(a0[j], 0.f);
    float r1 = fmaxf(a1[j], 0.f);
    float s = r0 + r1;
    for (int msk = 1; msk < 64; msk <<= 1) s += __shfl_xor(s, msk);
    float mean = s * (1.0f / 128.0f);
    float d0 = r0 - mean;
    float d1 = r1 - mean;
    float sq = d0 * d0 + d1 * d1;
    for (int msk = 1; msk < 64; msk <<= 1) sq += __shfl_xor(sq, msk);
    float rstd = rsqrtf(sq * (1.0f / 128.0f) + 1e-5f);
    if (node < N) {
      float2 o;
      o.x = d0 * rstd * g.x + b.x;
      o.y = d1 * rstd * g.y + b.y;
      *(float2*)(out + (size_t)node * HID + c0) = o;
    }
  }
}

extern "C" void kernel_launch(void* const* d_in, const int* in_sizes, int n_in,
                              void* d_out, int out_size, void* d_ws,
                              size_t ws_size, hipStream_t stream) {
  (void)n_in;
  (void)out_size;

  const int* edge_index = (const int*)d_in[0];
  const float* hX    = (const float*)d_in[1];
  const float* h_t   = (const float*)d_in[2];
  const float* Wq    = (const float*)d_in[3];
  const float* bq    = (const float*)d_in[4];
  const float* Wk    = (const float*)d_in[5];
  const float* bk    = (const float*)d_in[6];
  const float* Wv    = (const float*)d_in[7];
  const float* bv    = (const float*)d_in[8];
  const float* Wskip = (const float*)d_in[9];
  const float* bskip = (const float*)d_in[10];
  const float* Wup   = (const float*)d_in[11];
  const float* bup   = (const float*)d_in[12];
  const float* gamma = (const float*)d_in[13];
  const float* beta  = (const float*)d_in[14];

  const int E = in_sizes[0] / 2;
  const int N = in_sizes[1] / HID;
  const int* src_idx = edge_index;
  const int* dst_idx = edge_index + E;
  const int NB = (N + 255) / 256;
  const int NTILES = (N + 15) / 16;
  const int NTILES4 = ((NTILES + 3) / 4) * 4;

  // ---- workspace layout ----
  char* w = (char*)d_ws;
  size_t off = 0;
  float* cvec = (float*)(w + off);
  off += 256 * 4;
  int* deg = (int*)(w + off);
  off += ((size_t)N * 4 + 255) / 256 * 256;
  int* row_ptr = (int*)(w + off);
  off += ((size_t)(N + 1) * 4 + 255) / 256 * 256;
  int* cursor = (int*)(w + off);
  off += ((size_t)N * 4 + 255) / 256 * 256;
  int* bsums = (int*)(w + off);
  off += ((size_t)NB * 4 + 255) / 256 * 256;
  int* boffs = (int*)(w + off);
  off += ((size_t)NB * 4 + 255) / 256 * 256;
  int* col = (int*)(w + off);
  off += ((size_t)E * 4 + 255) / 256 * 256;
  float* scores = (float*)(w + off);
  off += ((size_t)E * HEADS * 4 + 255) / 256 * 256;
  u16* hpack = (u16*)(w + off);
  off += ((size_t)NTILES4 * 2048 * 2 + 255) / 256 * 256;
  u16* Wp1 = (u16*)(w + off);
  off += ((size_t)128 * 1024 * 2 + 255) / 256 * 256;
  u16* Wp2 = (u16*)(w + off);
  off += ((size_t)128 * 640 * 2 + 255) / 256 * 256;
  u16* bigA = (u16*)(w + off);   // q
  off += ((size_t)N * HC * 2 + 255) / 256 * 256;
  u16* bigB = (u16*)(w + off);   // k
  off += ((size_t)N * HC * 2 + 255) / 256 * 256;
  // third buffer (v) for the fused path — only if ws_size allows
  u16* bigC = (u16*)(w + off);
  size_t off_fused = off + ((size_t)N * HC * 2 + 255) / 256 * 256;
  // fused path: q,k,v coexist -> fused score+softmax+aggregate (4x MLP).
  // fallback: v overwrites q (bigA), split score->attn via scores buffer.
  const int use_fused = (ws_size >= off_fused) ? 1 : 0;

  float* out = (float*)d_out;

  // ---- CSR build (parallel 3-phase scan) ----
  zero_kernel<<<NB, 256, 0, stream>>>(deg, N);
  hist_kernel<<<(E + 255) / 256, 256, 0, stream>>>(dst_idx, deg, E);
  blocksum_kernel<<<NB, 256, 0, stream>>>(deg, bsums, N);
  scanb_kernel<<<1, 256, 0, stream>>>(bsums, boffs, NB);
  scanfinal_kernel<<<NB, 256, 0, stream>>>(deg, boffs, row_ptr, cursor, N);
  scatter_kernel<<<(E + 255) / 256, 256, 0, stream>>>(src_idx, dst_idx, cursor,
                                                      col, E);

  // ---- packing for MFMA ----
  int totH = NTILES4 * 2048;
  packH_kernel<<<(totH + 255) / 256, 256, 0, stream>>>(hX, hpack, N, totH);
  packW_kernel<<<(128 * 1024 + 255) / 256, 256, 0, stream>>>(
      Wq, Wk, 512, HC, HC, Wp1, 128 * 1024);
  packW_kernel<<<(128 * 640 + 255) / 256, 256, 0, stream>>>(
      Wv, Wskip, 512, HC, HID, Wp2, 128 * 640);

  // ---- cvec ----
  cvec_kernel<<<1, 128, 0, stream>>>(h_t, Wup, bup, cvec);

  // ---- MFMA projections: q -> bigA, k -> bigB ----
  mfma_proj_kernel<<<dim3(NTILES4 / 4, 16), 256, 0, stream>>>(
      hpack, Wp1, bq, bk, bigA, bigB, (float*)nullptr, 0, N);

  if (use_fused) {
    // ---- v -> bigC, skip -> d_out ----
    mfma_proj_kernel<<<dim3(NTILES4 / 4, 10), 256, 0, stream>>>(
        hpack, Wp2, bv, bskip, bigC, (u16*)nullptr, out, 1, N);
    // ---- fused score + online softmax + aggregate ----
    fused_attn_kernel<<<(N + 3) / 4, 256, 0, stream>>>(bigA, bigB, bigC,
                                                       row_ptr, col, out, N);
  } else {
    // ---- split fallback ----
    score_kernel<<<(N + 3) / 4, 256, 0, stream>>>(bigA, bigB, row_ptr, col,
                                                  scores, N);
    mfma_proj_kernel<<<dim3(NTILES4 / 4, 10), 256, 0, stream>>>(
        hpack, Wp2, bv, bskip, bigA, (u16*)nullptr, out, 1, N);
    attn_kernel<<<(N + 3) / 4, 256, 0, stream>>>(scores, bigA, row_ptr, col,
                                                 out, N);
  }

  // ---- update GEMM + relu + LayerNorm, in-place on d_out (tiled) ----
  ATTLayer_19396072308956_kernel<<<(N + UT - 1) / UT, 256, 0, stream>>>(
      out, Wup, cvec, gamma, beta, N);
}